// Round 1
// baseline (686.896 us; speedup 1.0000x reference)
//
#include <hip/hip_runtime.h>
#include <hip/hip_bf16.h>
#include <math.h>

#define DIMN   1024
#define HEADS  16
#define DHEAD  64
#define CTXD   768
#define FFH    4096
#define NTOK   4096
#define SEQ    2048
#define NCTX   77
#define CTOK   154

typedef unsigned short u16;
typedef __bf16 bf16x8 __attribute__((ext_vector_type(8)));
typedef float  f32x4  __attribute__((ext_vector_type(4)));

__device__ __forceinline__ u16 f2bf(float f) {
  union { float f; unsigned u; } c; c.f = f;
  unsigned r = c.u + 0x7FFFu + ((c.u >> 16) & 1u);
  return (u16)(r >> 16);
}
__device__ __forceinline__ float bf2f(u16 h) {
  union { unsigned u; float f; } c; c.u = ((unsigned)h) << 16; return c.f;
}

__device__ __forceinline__ void gload16(const void* g, void* l) {
  __builtin_amdgcn_global_load_lds(
      (__attribute__((address_space(1))) void*)(void*)(g),
      (__attribute__((address_space(3))) void*)(l), 16, 0, 0);
}

__device__ __forceinline__ f32x4 mfma16(bf16x8 a, bf16x8 b, f32x4 c) {
  return __builtin_amdgcn_mfma_f32_16x16x32_bf16(a, b, c, 0, 0, 0);
}

// ---------------- weight convert + transpose:  W[K][N] f32 -> WT[N][K] bf16
__global__ __launch_bounds__(256)
void wconv_k(const float* __restrict__ W, u16* __restrict__ WT, int K, int N)
{
  __shared__ u16 t[64][65];
  int n0 = blockIdx.x * 64, k0 = blockIdx.y * 64;
  int tid = threadIdx.x;
  int rr = tid >> 4, cc = tid & 15;
#pragma unroll
  for (int i = 0; i < 4; ++i) {
    int kr = rr + i * 16;
    const float4 v = *(const float4*)&W[(size_t)(k0 + kr) * N + n0 + cc * 4];
    t[kr][cc*4+0] = f2bf(v.x); t[kr][cc*4+1] = f2bf(v.y);
    t[kr][cc*4+2] = f2bf(v.z); t[kr][cc*4+3] = f2bf(v.w);
  }
  __syncthreads();
#pragma unroll
  for (int i = 0; i < 4; ++i) {
    int nr = rr + i * 16;
    int r0 = cc * 4;
    ushort4 o;
    o.x = t[r0+0][nr]; o.y = t[r0+1][nr]; o.z = t[r0+2][nr]; o.w = t[r0+3][nr];
    *(ushort4*)&WT[(size_t)(n0 + nr) * K + k0 + r0] = o;
  }
}

// ---------------- f32 -> bf16 elementwise (context)
__global__ void cconv_k(const float* __restrict__ c, u16* __restrict__ o, int n)
{
  int i = blockIdx.x * 256 + threadIdx.x;
  if (i < n) o[i] = f2bf(c[i]);
}

// ---------------- LayerNorm: f32 row[1024] -> bf16
__global__ __launch_bounds__(256)
void ln_k(const float* __restrict__ x, const float* __restrict__ gm,
          const float* __restrict__ bt, u16* __restrict__ o)
{
  int row = blockIdx.x;
  int tid = threadIdx.x;
  const float4 v = *(const float4*)&x[(size_t)row * DIMN + tid * 4];
  float s = v.x + v.y + v.z + v.w;
  float q = v.x*v.x + v.y*v.y + v.z*v.z + v.w*v.w;
#pragma unroll
  for (int off = 32; off; off >>= 1) { s += __shfl_xor(s, off); q += __shfl_xor(q, off); }
  __shared__ float ss[4], qq[4];
  int wave = tid >> 6;
  if ((tid & 63) == 0) { ss[wave] = s; qq[wave] = q; }
  __syncthreads();
  s = ss[0] + ss[1] + ss[2] + ss[3];
  q = qq[0] + qq[1] + qq[2] + qq[3];
  float mu = s * (1.0f / DIMN);
  float var = q * (1.0f / DIMN) - mu * mu;
  float rs = rsqrtf(var + 1e-5f);
  const float4 gv = *(const float4*)&gm[tid * 4];
  const float4 bv = *(const float4*)&bt[tid * 4];
  ushort4 r;
  r.x = f2bf((v.x - mu) * rs * gv.x + bv.x);
  r.y = f2bf((v.y - mu) * rs * gv.y + bv.y);
  r.z = f2bf((v.z - mu) * rs * gv.z + bv.z);
  r.w = f2bf((v.w - mu) * rs * gv.w + bv.w);
  *(ushort4*)&o[(size_t)row * DIMN + tid * 4] = r;
}

// ---------------- GEMM: A[M][K] bf16 row-major, Bt[N][K] bf16 (B transposed)
// MODE 0: out bf16 = acc + bias
// MODE 1: GEGLU: obf[r][c] = obf[r][c] * gelu(acc + bias)
// MODE 2: out f32 = acc + bias + resid
// MODE 3: vt store: obf[(b*1024+col)*vstride + (row%seq)] = bf16(acc)
template<int MODE>
__global__ __launch_bounds__(256, 2)
void gemm_k(const u16* __restrict__ A, const u16* __restrict__ Bt,
            int M, int N, int K,
            const float* __restrict__ bias, const float* __restrict__ resid,
            u16* __restrict__ obf, float* __restrict__ of32,
            int seq, int vstride)
{
  __shared__ __align__(16) u16 As[128 * 32];
  __shared__ __align__(16) u16 Bs[128 * 32];
  const int tid = threadIdx.x;
  const int lane = tid & 63, wave = tid >> 6;
  const int wr = wave >> 1, wc = wave & 1;
  const int g = lane >> 4, r16 = lane & 15;
  const int m0 = blockIdx.x * 128, n0 = blockIdx.y * 128;

  f32x4 acc[4][4] = {};

  const int srow = tid >> 2;
  const int scph = tid & 3;

  for (int kt = 0; kt < K; kt += 32) {
    __syncthreads();
#pragma unroll
    for (int is = 0; is < 2; ++is) {
      int r = srow + is * 64;
      int clog = scph ^ ((r >> 1) & 3);
      int ar = m0 + r; if (ar > M - 1) ar = M - 1;
      gload16(A + (size_t)ar * K + kt + clog * 8, &As[(r * 4 + scph) * 8]);
    }
#pragma unroll
    for (int is = 0; is < 2; ++is) {
      int r = srow + is * 64;
      int clog = scph ^ ((r >> 1) & 3);
      gload16(Bt + (size_t)(n0 + r) * K + kt + clog * 8, &Bs[(r * 4 + scph) * 8]);
    }
    asm volatile("s_waitcnt vmcnt(0)" ::: "memory");
    __syncthreads();

    bf16x8 af[4], bfr[4];
#pragma unroll
    for (int mi = 0; mi < 4; ++mi) {
      int r = wr * 64 + mi * 16 + r16;
      int cph = g ^ ((r >> 1) & 3);
      af[mi] = *(const bf16x8*)&As[(r * 4 + cph) * 8];
    }
#pragma unroll
    for (int ni = 0; ni < 4; ++ni) {
      int r = wc * 64 + ni * 16 + r16;
      int cph = g ^ ((r >> 1) & 3);
      bfr[ni] = *(const bf16x8*)&Bs[(r * 4 + cph) * 8];
    }
#pragma unroll
    for (int mi = 0; mi < 4; ++mi)
#pragma unroll
      for (int ni = 0; ni < 4; ++ni)
        acc[mi][ni] = mfma16(af[mi], bfr[ni], acc[mi][ni]);
  }

#pragma unroll
  for (int ni = 0; ni < 4; ++ni) {
    int col = n0 + wc * 64 + ni * 16 + r16;
    float bv = bias ? bias[col] : 0.0f;
#pragma unroll
    for (int mi = 0; mi < 4; ++mi) {
      f32x4 c = acc[mi][ni];
#pragma unroll
      for (int rg = 0; rg < 4; ++rg) {
        int row = m0 + wr * 64 + mi * 16 + g * 4 + rg;
        if (row < M) {
          float v = c[rg] + bv;
          if constexpr (MODE == 0) {
            obf[(size_t)row * N + col] = f2bf(v);
          } else if constexpr (MODE == 1) {
            size_t o = (size_t)row * N + col;
            float a = bf2f(obf[o]);
            float gl = 0.5f * v * (1.0f + erff(v * 0.70710678f));
            obf[o] = f2bf(a * gl);
          } else if constexpr (MODE == 2) {
            size_t o = (size_t)row * N + col;
            of32[o] = v + resid[o];
          } else {
            int b = row / seq, srow_ = row - b * seq;
            obf[((size_t)b * HEADS * DHEAD + col) * vstride + srow_] = f2bf(v);
          }
        }
      }
    }
  }
}

// ---------------- flash attention
// q: [B*SEQ][1024] bf16, k: [B*seqk][1024] bf16, vt: [b][h][d][vstride] bf16
// o: [B*SEQ][1024] bf16
__global__ __launch_bounds__(256)
void attn_k(const u16* __restrict__ q, const u16* __restrict__ k,
            const u16* __restrict__ vt, u16* __restrict__ o,
            int kvlen, int seqk, int vstride)
{
  __shared__ __align__(16) u16 Ks[32 * 64];
  __shared__ __align__(16) u16 Vs[64 * 32];
  __shared__ __align__(16) u16 Ps[4][16 * 40];
  const int tid = threadIdx.x, lane = tid & 63, wave = tid >> 6;
  const int g = lane >> 4, r16 = lane & 15;
  const int bh = blockIdx.y;
  const int b = bh >> 4, h = bh & 15;
  const int q0 = blockIdx.x * 64 + wave * 16;

  const size_t qoff = (size_t)(b * SEQ + q0 + r16) * DIMN + h * DHEAD;
  const bf16x8 aq0 = *(const bf16x8*)&q[qoff + g * 8];
  const bf16x8 aq1 = *(const bf16x8*)&q[qoff + 32 + g * 8];

  f32x4 oacc[4] = {};
  float mi[4] = { -3e38f, -3e38f, -3e38f, -3e38f };
  float li[4] = {};

  const int krow = tid >> 3, kcph = tid & 7;   // K stage: 32 rows x 8 chunks
  const int vd = tid >> 2,  vc = tid & 3;      // V stage: 64 rows x 4 chunks
  const size_t vtbase = (size_t)(b * HEADS + h) * DHEAD * vstride;

  const int nkv = (kvlen + 31) / 32;
  for (int kvb = 0; kvb < nkv; ++kvb) {
    const int kv0 = kvb * 32;
    __syncthreads();
    {
      int kr = kv0 + krow; if (kr > kvlen - 1) kr = kvlen - 1;
      int clog = kcph ^ (krow & 7);
      gload16(k + (size_t)(b * seqk + kr) * DIMN + h * DHEAD + clog * 8, &Ks[tid * 8]);
      gload16(vt + vtbase + (size_t)vd * vstride + kv0 + vc * 8, &Vs[tid * 8]);
    }
    asm volatile("s_waitcnt vmcnt(0)" ::: "memory");
    __syncthreads();

    f32x4 s0 = {}, s1 = {};
    {
      int kvloc = r16;
      int c0 = (g) ^ (kvloc & 7);
      int c1 = (4 + g) ^ (kvloc & 7);
      bf16x8 kf0 = *(const bf16x8*)&Ks[kvloc * 64 + c0 * 8];
      bf16x8 kf1 = *(const bf16x8*)&Ks[kvloc * 64 + c1 * 8];
      s0 = mfma16(aq0, kf0, s0);
      s0 = mfma16(aq1, kf1, s0);
      kvloc = 16 + r16;
      c0 = (g) ^ (kvloc & 7);
      c1 = (4 + g) ^ (kvloc & 7);
      kf0 = *(const bf16x8*)&Ks[kvloc * 64 + c0 * 8];
      kf1 = *(const bf16x8*)&Ks[kvloc * 64 + c1 * 8];
      s1 = mfma16(aq0, kf0, s1);
      s1 = mfma16(aq1, kf1, s1);
    }

    float sc0[4], sc1[4];
    const bool m0bad = (kv0 + r16 >= kvlen);
    const bool m1bad = (kv0 + 16 + r16 >= kvlen);
#pragma unroll
    for (int rg = 0; rg < 4; ++rg) {
      sc0[rg] = m0bad ? -3e38f : s0[rg] * 0.125f;
      sc1[rg] = m1bad ? -3e38f : s1[rg] * 0.125f;
    }
#pragma unroll
    for (int rg = 0; rg < 4; ++rg) {
      float mx = fmaxf(sc0[rg], sc1[rg]);
#pragma unroll
      for (int off = 8; off; off >>= 1) mx = fmaxf(mx, __shfl_xor(mx, off));
      float nm = fmaxf(mi[rg], mx);
      float corr = __expf(mi[rg] - nm);
      float p0 = __expf(sc0[rg] - nm);
      float p1 = __expf(sc1[rg] - nm);
      float rs = p0 + p1;
#pragma unroll
      for (int off = 8; off; off >>= 1) rs += __shfl_xor(rs, off);
      li[rg] = li[rg] * corr + rs;
      mi[rg] = nm;
#pragma unroll
      for (int nd = 0; nd < 4; ++nd) oacc[nd][rg] *= corr;
      Ps[wave][(g * 4 + rg) * 40 + r16]      = f2bf(p0);
      Ps[wave][(g * 4 + rg) * 40 + 16 + r16] = f2bf(p1);
    }

    const bf16x8 pf = *(const bf16x8*)&Ps[wave][r16 * 40 + g * 8];
#pragma unroll
    for (int nd = 0; nd < 4; ++nd) {
      bf16x8 vf = *(const bf16x8*)&Vs[(nd * 16 + r16) * 32 + g * 8];
      oacc[nd] = mfma16(pf, vf, oacc[nd]);
    }
  }

#pragma unroll
  for (int nd = 0; nd < 4; ++nd)
#pragma unroll
    for (int rg = 0; rg < 4; ++rg) {
      int row = q0 + g * 4 + rg;
      float v = oacc[nd][rg] / li[rg];
      o[(size_t)(b * SEQ + row) * DIMN + h * DHEAD + nd * 16 + r16] = f2bf(v);
    }
}

extern "C" void kernel_launch(void* const* d_in, const int* in_sizes, int n_in,
                              void* d_out, int out_size, void* d_ws, size_t ws_size,
                              hipStream_t stream)
{
  const float* x   = (const float*)d_in[0];
  const float* ctx = (const float*)d_in[1];
  const float* Wq1 = (const float*)d_in[2];
  const float* Wk1 = (const float*)d_in[3];
  const float* Wv1 = (const float*)d_in[4];
  const float* Wo1 = (const float*)d_in[5];
  const float* bo1 = (const float*)d_in[6];
  const float* Wq2 = (const float*)d_in[7];
  const float* Wk2 = (const float*)d_in[8];
  const float* Wv2 = (const float*)d_in[9];
  const float* Wo2 = (const float*)d_in[10];
  const float* bo2 = (const float*)d_in[11];
  const float* Wp  = (const float*)d_in[12];
  const float* bp  = (const float*)d_in[13];
  const float* W2  = (const float*)d_in[14];
  const float* b2  = (const float*)d_in[15];
  const float* g1  = (const float*)d_in[16];
  const float* be1 = (const float*)d_in[17];
  const float* g2  = (const float*)d_in[18];
  const float* be2 = (const float*)d_in[19];
  const float* g3  = (const float*)d_in[20];
  const float* be3 = (const float*)d_in[21];

  char* ws = (char*)d_ws;
  size_t off = 0;
  auto alloc = [&](size_t bytes) -> void* {
    void* p = ws + off;
    off += (bytes + 255) & ~(size_t)255;
    return p;
  };

  u16* WqT1 = (u16*)alloc((size_t)1024 * 1024 * 2);
  u16* WkT1 = (u16*)alloc((size_t)1024 * 1024 * 2);
  u16* WvT1 = (u16*)alloc((size_t)1024 * 1024 * 2);
  u16* WoT1 = (u16*)alloc((size_t)1024 * 1024 * 2);
  u16* WqT2 = (u16*)alloc((size_t)1024 * 1024 * 2);
  u16* WkT2 = (u16*)alloc((size_t)1024 * 768 * 2);
  u16* WvT2 = (u16*)alloc((size_t)1024 * 768 * 2);
  u16* WoT2 = (u16*)alloc((size_t)1024 * 1024 * 2);
  u16* WpT  = (u16*)alloc((size_t)8192 * 1024 * 2);
  u16* W2T  = (u16*)alloc((size_t)1024 * 4096 * 2);
  float* x1f = (float*)alloc((size_t)NTOK * DIMN * 4);
  float* x2f = (float*)alloc((size_t)NTOK * DIMN * 4);
  u16* ctxb = (u16*)alloc((size_t)CTOK * CTXD * 2);
  u16* k2b  = (u16*)alloc((size_t)CTOK * DIMN * 2);
  u16* vt2b = (u16*)alloc((size_t)2 * HEADS * DHEAD * 96 * 2);
  u16* hb   = (u16*)alloc((size_t)NTOK * DIMN * 2);
  u16* qb   = (u16*)alloc((size_t)NTOK * DIMN * 2);
  u16* kb   = (u16*)alloc((size_t)NTOK * DIMN * 2);
  u16* vtb  = (u16*)alloc((size_t)NTOK * DIMN * 2);
  u16* ab   = (u16*)alloc((size_t)NTOK * DIMN * 2);
  u16* ub   = qb; // reuse qb..ab region (32MB) for FF intermediate [4096][4096]

  dim3 blk(256);

  // weight conversions (f32 [K][N] -> bf16 [N][K])
  wconv_k<<<dim3(16, 16), blk, 0, stream>>>(Wq1, WqT1, 1024, 1024);
  wconv_k<<<dim3(16, 16), blk, 0, stream>>>(Wk1, WkT1, 1024, 1024);
  wconv_k<<<dim3(16, 16), blk, 0, stream>>>(Wv1, WvT1, 1024, 1024);
  wconv_k<<<dim3(16, 16), blk, 0, stream>>>(Wo1, WoT1, 1024, 1024);
  wconv_k<<<dim3(16, 16), blk, 0, stream>>>(Wq2, WqT2, 1024, 1024);
  wconv_k<<<dim3(16, 12), blk, 0, stream>>>(Wk2, WkT2, 768, 1024);
  wconv_k<<<dim3(16, 12), blk, 0, stream>>>(Wv2, WvT2, 768, 1024);
  wconv_k<<<dim3(16, 16), blk, 0, stream>>>(Wo2, WoT2, 1024, 1024);
  wconv_k<<<dim3(128, 16), blk, 0, stream>>>(Wp, WpT, 1024, 8192);
  wconv_k<<<dim3(16, 64), blk, 0, stream>>>(W2, W2T, 4096, 1024);
  cconv_k<<<dim3((CTOK * CTXD + 255) / 256), blk, 0, stream>>>(ctx, ctxb, CTOK * CTXD);

  // ---- self attention block
  ln_k<<<NTOK, 256, 0, stream>>>(x, g1, be1, hb);
  gemm_k<0><<<dim3(32, 8), blk, 0, stream>>>(hb, WqT1, NTOK, 1024, 1024, nullptr, nullptr, qb, nullptr, 0, 0);
  gemm_k<0><<<dim3(32, 8), blk, 0, stream>>>(hb, WkT1, NTOK, 1024, 1024, nullptr, nullptr, kb, nullptr, 0, 0);
  gemm_k<3><<<dim3(32, 8), blk, 0, stream>>>(hb, WvT1, NTOK, 1024, 1024, nullptr, nullptr, vtb, nullptr, SEQ, SEQ);
  attn_k<<<dim3(32, 32), blk, 0, stream>>>(qb, kb, vtb, ab, SEQ, SEQ, SEQ);
  gemm_k<2><<<dim3(32, 8), blk, 0, stream>>>(ab, WoT1, NTOK, 1024, 1024, bo1, x, nullptr, x1f, 0, 0);

  // ---- cross attention block
  ln_k<<<NTOK, 256, 0, stream>>>(x1f, g2, be2, hb);
  gemm_k<0><<<dim3(32, 8), blk, 0, stream>>>(hb, WqT2, NTOK, 1024, 1024, nullptr, nullptr, qb, nullptr, 0, 0);
  gemm_k<0><<<dim3(2, 8), blk, 0, stream>>>(ctxb, WkT2, CTOK, 1024, 768, nullptr, nullptr, k2b, nullptr, 0, 0);
  gemm_k<3><<<dim3(2, 8), blk, 0, stream>>>(ctxb, WvT2, CTOK, 1024, 768, nullptr, nullptr, vt2b, nullptr, NCTX, 96);
  attn_k<<<dim3(32, 32), blk, 0, stream>>>(qb, k2b, vt2b, ab, NCTX, NCTX, 96);
  gemm_k<2><<<dim3(32, 8), blk, 0, stream>>>(ab, WoT2, NTOK, 1024, 1024, bo2, x1f, nullptr, x2f, 0, 0);

  // ---- GEGLU FF block
  ln_k<<<NTOK, 256, 0, stream>>>(x2f, g3, be3, hb);
  gemm_k<0><<<dim3(32, 32), blk, 0, stream>>>(hb, WpT, NTOK, FFH, 1024, bp, nullptr, ub, nullptr, 0, 0);
  gemm_k<1><<<dim3(32, 32), blk, 0, stream>>>(hb, WpT + (size_t)4096 * 1024, NTOK, FFH, 1024, bp + 4096, nullptr, ub, nullptr, 0, 0);
  gemm_k<2><<<dim3(32, 8), blk, 0, stream>>>(ub, W2T, NTOK, 1024, 4096, b2, x2f, nullptr, (float*)d_out, 0, 0);

  (void)in_sizes; (void)n_in; (void)out_size; (void)ws_size;
}

// Round 2
// 666.165 us; speedup vs baseline: 1.0311x; 1.0311x over previous
//
#include <hip/hip_runtime.h>
#include <hip/hip_bf16.h>
#include <math.h>

#define DIMN   1024
#define HEADS  16
#define DHEAD  64
#define CTXD   768
#define FFH    4096
#define NTOK   4096
#define SEQ    2048
#define NCTX   77
#define CTOK   154

typedef unsigned short u16;
typedef __bf16 bf16x8 __attribute__((ext_vector_type(8)));
typedef float  f32x4  __attribute__((ext_vector_type(4)));

__device__ __forceinline__ u16 f2bf(float f) {
  union { float f; unsigned u; } c; c.f = f;
  unsigned r = c.u + 0x7FFFu + ((c.u >> 16) & 1u);
  return (u16)(r >> 16);
}
__device__ __forceinline__ float bf2f(u16 h) {
  union { unsigned u; float f; } c; c.u = ((unsigned)h) << 16; return c.f;
}

__device__ __forceinline__ void gload16(const void* g, void* l) {
  __builtin_amdgcn_global_load_lds(
      (__attribute__((address_space(1))) void*)(void*)(g),
      (__attribute__((address_space(3))) void*)(l), 16, 0, 0);
}

__device__ __forceinline__ f32x4 mfma16(bf16x8 a, bf16x8 b, f32x4 c) {
  return __builtin_amdgcn_mfma_f32_16x16x32_bf16(a, b, c, 0, 0, 0);
}

// ---------------- weight convert + transpose:  W[K][N] f32 -> WT[N][K] bf16
__global__ __launch_bounds__(256)
void wconv_k(const float* __restrict__ W, u16* __restrict__ WT, int K, int N)
{
  __shared__ u16 t[64][65];
  int n0 = blockIdx.x * 64, k0 = blockIdx.y * 64;
  int tid = threadIdx.x;
  int rr = tid >> 4, cc = tid & 15;
#pragma unroll
  for (int i = 0; i < 4; ++i) {
    int kr = rr + i * 16;
    const float4 v = *(const float4*)&W[(size_t)(k0 + kr) * N + n0 + cc * 4];
    t[kr][cc*4+0] = f2bf(v.x); t[kr][cc*4+1] = f2bf(v.y);
    t[kr][cc*4+2] = f2bf(v.z); t[kr][cc*4+3] = f2bf(v.w);
  }
  __syncthreads();
#pragma unroll
  for (int i = 0; i < 4; ++i) {
    int nr = rr + i * 16;
    int r0 = cc * 4;
    ushort4 o;
    o.x = t[r0+0][nr]; o.y = t[r0+1][nr]; o.z = t[r0+2][nr]; o.w = t[r0+3][nr];
    *(ushort4*)&WT[(size_t)(n0 + nr) * K + k0 + r0] = o;
  }
}

// ---------------- f32 -> bf16 elementwise (context)
__global__ void cconv_k(const float* __restrict__ c, u16* __restrict__ o, int n)
{
  int i = blockIdx.x * 256 + threadIdx.x;
  if (i < n) o[i] = f2bf(c[i]);
}

// ---------------- LayerNorm: f32 row[1024] -> bf16
__global__ __launch_bounds__(256)
void ln_k(const float* __restrict__ x, const float* __restrict__ gm,
          const float* __restrict__ bt, u16* __restrict__ o)
{
  int row = blockIdx.x;
  int tid = threadIdx.x;
  const float4 v = *(const float4*)&x[(size_t)row * DIMN + tid * 4];
  float s = v.x + v.y + v.z + v.w;
  float q = v.x*v.x + v.y*v.y + v.z*v.z + v.w*v.w;
#pragma unroll
  for (int off = 32; off; off >>= 1) { s += __shfl_xor(s, off); q += __shfl_xor(q, off); }
  __shared__ float ss[4], qq[4];
  int wave = tid >> 6;
  if ((tid & 63) == 0) { ss[wave] = s; qq[wave] = q; }
  __syncthreads();
  s = ss[0] + ss[1] + ss[2] + ss[3];
  q = qq[0] + qq[1] + qq[2] + qq[3];
  float mu = s * (1.0f / DIMN);
  float var = q * (1.0f / DIMN) - mu * mu;
  float rs = rsqrtf(var + 1e-5f);
  const float4 gv = *(const float4*)&gm[tid * 4];
  const float4 bv = *(const float4*)&bt[tid * 4];
  ushort4 r;
  r.x = f2bf((v.x - mu) * rs * gv.x + bv.x);
  r.y = f2bf((v.y - mu) * rs * gv.y + bv.y);
  r.z = f2bf((v.z - mu) * rs * gv.z + bv.z);
  r.w = f2bf((v.w - mu) * rs * gv.w + bv.w);
  *(ushort4*)&o[(size_t)row * DIMN + tid * 4] = r;
}

// ---------------- GEMM: A[M][K] bf16 row-major, Bt[N][K] bf16 (B transposed)
// MODE 0: out bf16 = acc + bias
// MODE 1: GEGLU: obf[r][c] = obf[r][c] * gelu(acc + bias)
// MODE 2: out f32 = acc + bias + resid
// MODE 3: vt store: obf[(b*1024+col)*vstride + (row%seq)] = bf16(acc)
template<int MODE>
__global__ __launch_bounds__(256, 2)
void gemm_k(const u16* __restrict__ A, const u16* __restrict__ Bt,
            int M, int N, int K,
            const float* __restrict__ bias, const float* __restrict__ resid,
            u16* __restrict__ obf, float* __restrict__ of32,
            int seq, int vstride)
{
  __shared__ __align__(16) u16 As[128 * 32];
  __shared__ __align__(16) u16 Bs[128 * 32];
  const int tid = threadIdx.x;
  const int lane = tid & 63, wave = tid >> 6;
  const int wr = wave >> 1, wc = wave & 1;
  const int g = lane >> 4, r16 = lane & 15;
  const int m0 = blockIdx.x * 128, n0 = blockIdx.y * 128;

  f32x4 acc[4][4] = {};

  const int srow = tid >> 2;
  const int scph = tid & 3;

  for (int kt = 0; kt < K; kt += 32) {
    __syncthreads();
#pragma unroll
    for (int is = 0; is < 2; ++is) {
      int r = srow + is * 64;
      int clog = scph ^ ((r >> 1) & 3);
      int ar = m0 + r; if (ar > M - 1) ar = M - 1;
      gload16(A + (size_t)ar * K + kt + clog * 8, &As[(r * 4 + scph) * 8]);
    }
#pragma unroll
    for (int is = 0; is < 2; ++is) {
      int r = srow + is * 64;
      int clog = scph ^ ((r >> 1) & 3);
      gload16(Bt + (size_t)(n0 + r) * K + kt + clog * 8, &Bs[(r * 4 + scph) * 8]);
    }
    asm volatile("s_waitcnt vmcnt(0)" ::: "memory");
    __syncthreads();

    bf16x8 af[4], bfr[4];
#pragma unroll
    for (int mi = 0; mi < 4; ++mi) {
      int r = wr * 64 + mi * 16 + r16;
      int cph = g ^ ((r >> 1) & 3);
      af[mi] = *(const bf16x8*)&As[(r * 4 + cph) * 8];
    }
#pragma unroll
    for (int ni = 0; ni < 4; ++ni) {
      int r = wc * 64 + ni * 16 + r16;
      int cph = g ^ ((r >> 1) & 3);
      bfr[ni] = *(const bf16x8*)&Bs[(r * 4 + cph) * 8];
    }
#pragma unroll
    for (int mi = 0; mi < 4; ++mi)
#pragma unroll
      for (int ni = 0; ni < 4; ++ni)
        acc[mi][ni] = mfma16(af[mi], bfr[ni], acc[mi][ni]);
  }

#pragma unroll
  for (int ni = 0; ni < 4; ++ni) {
    int col = n0 + wc * 64 + ni * 16 + r16;
    float bv = bias ? bias[col] : 0.0f;
#pragma unroll
    for (int mi = 0; mi < 4; ++mi) {
      f32x4 c = acc[mi][ni];
#pragma unroll
      for (int rg = 0; rg < 4; ++rg) {
        int row = m0 + wr * 64 + mi * 16 + g * 4 + rg;
        if (row < M) {
          float v = c[rg] + bv;
          if constexpr (MODE == 0) {
            obf[(size_t)row * N + col] = f2bf(v);
          } else if constexpr (MODE == 1) {
            size_t o = (size_t)row * N + col;
            float a = bf2f(obf[o]);
            float gl = 0.5f * v * (1.0f + erff(v * 0.70710678f));
            obf[o] = f2bf(a * gl);
          } else if constexpr (MODE == 2) {
            size_t o = (size_t)row * N + col;
            of32[o] = v + resid[o];
          } else {
            int b = row / seq, srow_ = row - b * seq;
            obf[((size_t)b * HEADS * DHEAD + col) * vstride + srow_] = f2bf(v);
          }
        }
      }
    }
  }
}

// ---------------- flash attention v2
// 4 waves x 32 q rows = 128 q rows/block; KV tile 64, double-buffered.
// q: [B*SEQ][1024] bf16, k: [B*seqk][1024] bf16, vt: [b][h][d][vstride] bf16
// o: [B*SEQ][1024] bf16
__global__ __launch_bounds__(256)
void attn_k(const u16* __restrict__ q, const u16* __restrict__ k,
            const u16* __restrict__ vt, u16* __restrict__ o,
            int kvlen, int seqk, int vstride)
{
  __shared__ __align__(16) u16 Ks[2][64 * 64];   // [kv row][d], row-XOR-swizzled chunks
  __shared__ __align__(16) u16 Vs[2][64 * 64];   // [d row][kv], row-XOR-swizzled chunks
  __shared__ __align__(16) u16 Ps[4][32 * 72];   // per-wave P, stride 72 (144B, 16B-mult)
  const int tid = threadIdx.x, lane = tid & 63, wave = tid >> 6;
  const int g = lane >> 4, r16 = lane & 15;
  const int bh = blockIdx.y;
  const int b = bh >> 4, h = bh & 15;
  const int q0 = blockIdx.x * 128 + wave * 32;

  // Q fragments: aq[qsub][kchunk], row = q0+qsub*16+r16, d = kc*32+g*8
  bf16x8 aq[2][2];
#pragma unroll
  for (int qs = 0; qs < 2; ++qs) {
    const size_t qoff = (size_t)(b * SEQ + q0 + qs * 16 + r16) * DIMN + h * DHEAD;
#pragma unroll
    for (int kc = 0; kc < 2; ++kc)
      aq[qs][kc] = *(const bf16x8*)&q[qoff + kc * 32 + g * 8];
  }

  f32x4 oacc[2][4] = {};
  float mi[2][4], li[2][4];
#pragma unroll
  for (int qs = 0; qs < 2; ++qs)
#pragma unroll
    for (int rg = 0; rg < 4; ++rg) { mi[qs][rg] = -3e38f; li[qs][rg] = 0.f; }

  const size_t vtbase = (size_t)(b * HEADS + h) * DHEAD * vstride;
  const size_t kbase  = (size_t)b * seqk * DIMN + h * DHEAD;
  const int nkv = (kvlen + 63) >> 6;

  // stage K tile (64 rows x 8 chunks of 16B) + V^T tile, source-XOR-swizzled
  auto stage = [&](int buf, int kv0) {
#pragma unroll
    for (int i = 0; i < 2; ++i) {
      const int c = tid + i * 256;
      const int row = c >> 3, ch = c & 7;
      const int chs = ch ^ (row & 7);
      int kr = kv0 + row; if (kr > kvlen - 1) kr = kvlen - 1;
      gload16(k + kbase + (size_t)kr * DIMN + chs * 8, &Ks[buf][c * 8]);
    }
#pragma unroll
    for (int i = 0; i < 2; ++i) {
      const int c = tid + i * 256;
      const int row = c >> 3, ch = c & 7;
      const int chs = ch ^ (row & 7);
      gload16(vt + vtbase + (size_t)row * vstride + kv0 + chs * 8, &Vs[buf][c * 8]);
    }
  };

  stage(0, 0);
  asm volatile("s_waitcnt vmcnt(0)" ::: "memory");
  __syncthreads();

  for (int kvb = 0; kvb < nkv; ++kvb) {
    const int kv0 = kvb * 64;
    const int cur = kvb & 1;
    if (kvb + 1 < nkv) stage(cur ^ 1, kv0 + 64);   // prefetch flies under compute

    // ---- QK^T: 16 MFMA
    f32x4 sa[2][4];
#pragma unroll
    for (int qs = 0; qs < 2; ++qs)
#pragma unroll
      for (int st = 0; st < 4; ++st) sa[qs][st] = (f32x4){0.f, 0.f, 0.f, 0.f};
#pragma unroll
    for (int st = 0; st < 4; ++st) {
      const int kvr = st * 16 + r16;
#pragma unroll
      for (int kc = 0; kc < 2; ++kc) {
        const int chs = (kc * 4 + g) ^ (kvr & 7);
        const bf16x8 kf = *(const bf16x8*)&Ks[cur][kvr * 64 + chs * 8];
        sa[0][st] = mfma16(aq[0][kc], kf, sa[0][st]);
        sa[1][st] = mfma16(aq[1][kc], kf, sa[1][st]);
      }
    }

    // ---- online softmax (raw-units max; scale*log2e folded into exp2)
    const bool tmask = (kv0 + 64 > kvlen);
#pragma unroll
    for (int qs = 0; qs < 2; ++qs) {
#pragma unroll
      for (int rg = 0; rg < 4; ++rg) {
        float s0 = sa[qs][0][rg], s1 = sa[qs][1][rg];
        float s2 = sa[qs][2][rg], s3 = sa[qs][3][rg];
        if (tmask) {
          if (kv0 +      r16 >= kvlen) s0 = -3e38f;
          if (kv0 + 16 + r16 >= kvlen) s1 = -3e38f;
          if (kv0 + 32 + r16 >= kvlen) s2 = -3e38f;
          if (kv0 + 48 + r16 >= kvlen) s3 = -3e38f;
        }
        float mx = fmaxf(fmaxf(s0, s1), fmaxf(s2, s3));
#pragma unroll
        for (int off = 1; off < 16; off <<= 1) mx = fmaxf(mx, __shfl_xor(mx, off));
        const float nm = fmaxf(mi[qs][rg], mx);
        const float corr = exp2f((mi[qs][rg] - nm) * 0.18033688f);
        mi[qs][rg] = nm;
        const float p0 = exp2f((s0 - nm) * 0.18033688f);
        const float p1 = exp2f((s1 - nm) * 0.18033688f);
        const float p2 = exp2f((s2 - nm) * 0.18033688f);
        const float p3 = exp2f((s3 - nm) * 0.18033688f);
        float rs = (p0 + p1) + (p2 + p3);
#pragma unroll
        for (int off = 1; off < 16; off <<= 1) rs += __shfl_xor(rs, off);
        li[qs][rg] = li[qs][rg] * corr + rs;
#pragma unroll
        for (int ds = 0; ds < 4; ++ds) oacc[qs][ds][rg] *= corr;
        const int prow = qs * 16 + g * 4 + rg;
        Ps[wave][prow * 72 +      r16] = f2bf(p0);
        Ps[wave][prow * 72 + 16 + r16] = f2bf(p1);
        Ps[wave][prow * 72 + 32 + r16] = f2bf(p2);
        Ps[wave][prow * 72 + 48 + r16] = f2bf(p3);
      }
    }

    // ---- PV: 16 MFMA
#pragma unroll
    for (int kc = 0; kc < 2; ++kc) {
      const bf16x8 pa0 = *(const bf16x8*)&Ps[wave][(r16)      * 72 + kc * 32 + g * 8];
      const bf16x8 pa1 = *(const bf16x8*)&Ps[wave][(16 + r16) * 72 + kc * 32 + g * 8];
#pragma unroll
      for (int ds = 0; ds < 4; ++ds) {
        const int dr = ds * 16 + r16;
        const int chs = (kc * 4 + g) ^ (dr & 7);
        const bf16x8 vf = *(const bf16x8*)&Vs[cur][dr * 64 + chs * 8];
        oacc[0][ds] = mfma16(pa0, vf, oacc[0][ds]);
        oacc[1][ds] = mfma16(pa1, vf, oacc[1][ds]);
      }
    }

    asm volatile("s_waitcnt vmcnt(0)" ::: "memory");
    __syncthreads();
  }

#pragma unroll
  for (int qs = 0; qs < 2; ++qs)
#pragma unroll
    for (int rg = 0; rg < 4; ++rg) {
      const float inv = 1.0f / li[qs][rg];
      const int row = q0 + qs * 16 + g * 4 + rg;
      const size_t base = (size_t)(b * SEQ + row) * DIMN + h * DHEAD;
#pragma unroll
      for (int ds = 0; ds < 4; ++ds)
        o[base + ds * 16 + r16] = f2bf(oacc[qs][ds][rg] * inv);
    }
}

extern "C" void kernel_launch(void* const* d_in, const int* in_sizes, int n_in,
                              void* d_out, int out_size, void* d_ws, size_t ws_size,
                              hipStream_t stream)
{
  const float* x   = (const float*)d_in[0];
  const float* ctx = (const float*)d_in[1];
  const float* Wq1 = (const float*)d_in[2];
  const float* Wk1 = (const float*)d_in[3];
  const float* Wv1 = (const float*)d_in[4];
  const float* Wo1 = (const float*)d_in[5];
  const float* bo1 = (const float*)d_in[6];
  const float* Wq2 = (const float*)d_in[7];
  const float* Wk2 = (const float*)d_in[8];
  const float* Wv2 = (const float*)d_in[9];
  const float* Wo2 = (const float*)d_in[10];
  const float* bo2 = (const float*)d_in[11];
  const float* Wp  = (const float*)d_in[12];
  const float* bp  = (const float*)d_in[13];
  const float* W2  = (const float*)d_in[14];
  const float* b2  = (const float*)d_in[15];
  const float* g1  = (const float*)d_in[16];
  const float* be1 = (const float*)d_in[17];
  const float* g2  = (const float*)d_in[18];
  const float* be2 = (const float*)d_in[19];
  const float* g3  = (const float*)d_in[20];
  const float* be3 = (const float*)d_in[21];

  char* ws = (char*)d_ws;
  size_t off = 0;
  auto alloc = [&](size_t bytes) -> void* {
    void* p = ws + off;
    off += (bytes + 255) & ~(size_t)255;
    return p;
  };

  u16* WqT1 = (u16*)alloc((size_t)1024 * 1024 * 2);
  u16* WkT1 = (u16*)alloc((size_t)1024 * 1024 * 2);
  u16* WvT1 = (u16*)alloc((size_t)1024 * 1024 * 2);
  u16* WoT1 = (u16*)alloc((size_t)1024 * 1024 * 2);
  u16* WqT2 = (u16*)alloc((size_t)1024 * 1024 * 2);
  u16* WkT2 = (u16*)alloc((size_t)1024 * 768 * 2);
  u16* WvT2 = (u16*)alloc((size_t)1024 * 768 * 2);
  u16* WoT2 = (u16*)alloc((size_t)1024 * 1024 * 2);
  u16* WpT  = (u16*)alloc((size_t)8192 * 1024 * 2);
  u16* W2T  = (u16*)alloc((size_t)1024 * 4096 * 2);
  float* x1f = (float*)alloc((size_t)NTOK * DIMN * 4);
  float* x2f = (float*)alloc((size_t)NTOK * DIMN * 4);
  u16* ctxb = (u16*)alloc((size_t)CTOK * CTXD * 2);
  u16* k2b  = (u16*)alloc((size_t)CTOK * DIMN * 2);
  u16* vt2b = (u16*)alloc((size_t)2 * HEADS * DHEAD * 128 * 2);
  u16* hb   = (u16*)alloc((size_t)NTOK * DIMN * 2);
  u16* qb   = (u16*)alloc((size_t)NTOK * DIMN * 2);
  u16* kb   = (u16*)alloc((size_t)NTOK * DIMN * 2);
  u16* vtb  = (u16*)alloc((size_t)NTOK * DIMN * 2);
  u16* ab   = (u16*)alloc((size_t)NTOK * DIMN * 2);
  u16* ub   = qb; // reuse qb..ab region (32MB) for FF intermediate [4096][4096]

  dim3 blk(256);

  // weight conversions (f32 [K][N] -> bf16 [N][K])
  wconv_k<<<dim3(16, 16), blk, 0, stream>>>(Wq1, WqT1, 1024, 1024);
  wconv_k<<<dim3(16, 16), blk, 0, stream>>>(Wk1, WkT1, 1024, 1024);
  wconv_k<<<dim3(16, 16), blk, 0, stream>>>(Wv1, WvT1, 1024, 1024);
  wconv_k<<<dim3(16, 16), blk, 0, stream>>>(Wo1, WoT1, 1024, 1024);
  wconv_k<<<dim3(16, 16), blk, 0, stream>>>(Wq2, WqT2, 1024, 1024);
  wconv_k<<<dim3(16, 12), blk, 0, stream>>>(Wk2, WkT2, 768, 1024);
  wconv_k<<<dim3(16, 12), blk, 0, stream>>>(Wv2, WvT2, 768, 1024);
  wconv_k<<<dim3(16, 16), blk, 0, stream>>>(Wo2, WoT2, 1024, 1024);
  wconv_k<<<dim3(128, 16), blk, 0, stream>>>(Wp, WpT, 1024, 8192);
  wconv_k<<<dim3(16, 64), blk, 0, stream>>>(W2, W2T, 4096, 1024);
  cconv_k<<<dim3((CTOK * CTXD + 255) / 256), blk, 0, stream>>>(ctx, ctxb, CTOK * CTXD);

  // ---- self attention block
  ln_k<<<NTOK, 256, 0, stream>>>(x, g1, be1, hb);
  gemm_k<0><<<dim3(32, 8), blk, 0, stream>>>(hb, WqT1, NTOK, 1024, 1024, nullptr, nullptr, qb, nullptr, 0, 0);
  gemm_k<0><<<dim3(32, 8), blk, 0, stream>>>(hb, WkT1, NTOK, 1024, 1024, nullptr, nullptr, kb, nullptr, 0, 0);
  gemm_k<3><<<dim3(32, 8), blk, 0, stream>>>(hb, WvT1, NTOK, 1024, 1024, nullptr, nullptr, vtb, nullptr, SEQ, SEQ);
  attn_k<<<dim3(16, 32), blk, 0, stream>>>(qb, kb, vtb, ab, SEQ, SEQ, SEQ);
  gemm_k<2><<<dim3(32, 8), blk, 0, stream>>>(ab, WoT1, NTOK, 1024, 1024, bo1, x, nullptr, x1f, 0, 0);

  // ---- cross attention block
  ln_k<<<NTOK, 256, 0, stream>>>(x1f, g2, be2, hb);
  gemm_k<0><<<dim3(32, 8), blk, 0, stream>>>(hb, WqT2, NTOK, 1024, 1024, nullptr, nullptr, qb, nullptr, 0, 0);
  gemm_k<0><<<dim3(2, 8), blk, 0, stream>>>(ctxb, WkT2, CTOK, 1024, 768, nullptr, nullptr, k2b, nullptr, 0, 0);
  gemm_k<3><<<dim3(2, 8), blk, 0, stream>>>(ctxb, WvT2, CTOK, 1024, 768, nullptr, nullptr, vt2b, nullptr, NCTX, 128);
  attn_k<<<dim3(16, 32), blk, 0, stream>>>(qb, k2b, vt2b, ab, NCTX, NCTX, 128);
  gemm_k<2><<<dim3(32, 8), blk, 0, stream>>>(ab, WoT2, NTOK, 1024, 1024, bo2, x1f, nullptr, x2f, 0, 0);

  // ---- GEGLU FF block
  ln_k<<<NTOK, 256, 0, stream>>>(x2f, g3, be3, hb);
  gemm_k<0><<<dim3(32, 32), blk, 0, stream>>>(hb, WpT, NTOK, FFH, 1024, bp, nullptr, ub, nullptr, 0, 0);
  gemm_k<1><<<dim3(32, 32), blk, 0, stream>>>(hb, WpT + (size_t)4096 * 1024, NTOK, FFH, 1024, bp + 4096, nullptr, ub, nullptr, 0, 0);
  gemm_k<2><<<dim3(32, 8), blk, 0, stream>>>(ub, W2T, NTOK, 1024, 4096, b2, x2f, nullptr, (float*)d_out, 0, 0);

  (void)in_sizes; (void)n_in; (void)out_size; (void)ws_size;
}

// Round 3
// 587.181 us; speedup vs baseline: 1.1698x; 1.1345x over previous
//
#include <hip/hip_runtime.h>
#include <hip/hip_bf16.h>
#include <math.h>

#define DIMN   1024
#define HEADS  16
#define DHEAD  64
#define CTXD   768
#define FFH    4096
#define NTOK   4096
#define SEQ    2048
#define NCTX   77
#define CTOK   154

typedef unsigned short u16;
typedef __bf16 bf16x8 __attribute__((ext_vector_type(8)));
typedef float  f32x4  __attribute__((ext_vector_type(4)));

__device__ __forceinline__ u16 f2bf(float f) {
  union { float f; unsigned u; } c; c.f = f;
  unsigned r = c.u + 0x7FFFu + ((c.u >> 16) & 1u);
  return (u16)(r >> 16);
}
__device__ __forceinline__ float bf2f(u16 h) {
  union { unsigned u; float f; } c; c.u = ((unsigned)h) << 16; return c.f;
}

__device__ __forceinline__ void gload16(const void* g, void* l) {
  __builtin_amdgcn_global_load_lds(
      (__attribute__((address_space(1))) void*)(void*)(g),
      (__attribute__((address_space(3))) void*)(l), 16, 0, 0);
}

__device__ __forceinline__ f32x4 mfma16(bf16x8 a, bf16x8 b, f32x4 c) {
  return __builtin_amdgcn_mfma_f32_16x16x32_bf16(a, b, c, 0, 0, 0);
}

// ---------------- weight convert + transpose:  W[K][N] f32 -> WT[N][K] bf16
__global__ __launch_bounds__(256)
void wconv_k(const float* __restrict__ W, u16* __restrict__ WT, int K, int N)
{
  __shared__ u16 t[64][65];
  int n0 = blockIdx.x * 64, k0 = blockIdx.y * 64;
  int tid = threadIdx.x;
  int rr = tid >> 4, cc = tid & 15;
#pragma unroll
  for (int i = 0; i < 4; ++i) {
    int kr = rr + i * 16;
    const float4 v = *(const float4*)&W[(size_t)(k0 + kr) * N + n0 + cc * 4];
    t[kr][cc*4+0] = f2bf(v.x); t[kr][cc*4+1] = f2bf(v.y);
    t[kr][cc*4+2] = f2bf(v.z); t[kr][cc*4+3] = f2bf(v.w);
  }
  __syncthreads();
#pragma unroll
  for (int i = 0; i < 4; ++i) {
    int nr = rr + i * 16;
    int r0 = cc * 4;
    ushort4 o;
    o.x = t[r0+0][nr]; o.y = t[r0+1][nr]; o.z = t[r0+2][nr]; o.w = t[r0+3][nr];
    *(ushort4*)&WT[(size_t)(n0 + nr) * K + k0 + r0] = o;
  }
}

// ---------------- f32 -> bf16 elementwise (context)
__global__ void cconv_k(const float* __restrict__ c, u16* __restrict__ o, int n)
{
  int i = blockIdx.x * 256 + threadIdx.x;
  if (i < n) o[i] = f2bf(c[i]);
}

// ---------------- LayerNorm: f32 row[1024] -> bf16
__global__ __launch_bounds__(256)
void ln_k(const float* __restrict__ x, const float* __restrict__ gm,
          const float* __restrict__ bt, u16* __restrict__ o)
{
  int row = blockIdx.x;
  int tid = threadIdx.x;
  const float4 v = *(const float4*)&x[(size_t)row * DIMN + tid * 4];
  float s = v.x + v.y + v.z + v.w;
  float q = v.x*v.x + v.y*v.y + v.z*v.z + v.w*v.w;
#pragma unroll
  for (int off = 32; off; off >>= 1) { s += __shfl_xor(s, off); q += __shfl_xor(q, off); }
  __shared__ float ss[4], qq[4];
  int wave = tid >> 6;
  if ((tid & 63) == 0) { ss[wave] = s; qq[wave] = q; }
  __syncthreads();
  s = ss[0] + ss[1] + ss[2] + ss[3];
  q = qq[0] + qq[1] + qq[2] + qq[3];
  float mu = s * (1.0f / DIMN);
  float var = q * (1.0f / DIMN) - mu * mu;
  float rs = rsqrtf(var + 1e-5f);
  const float4 gv = *(const float4*)&gm[tid * 4];
  const float4 bv = *(const float4*)&bt[tid * 4];
  ushort4 r;
  r.x = f2bf((v.x - mu) * rs * gv.x + bv.x);
  r.y = f2bf((v.y - mu) * rs * gv.y + bv.y);
  r.z = f2bf((v.z - mu) * rs * gv.z + bv.z);
  r.w = f2bf((v.w - mu) * rs * gv.w + bv.w);
  *(ushort4*)&o[(size_t)row * DIMN + tid * 4] = r;
}

// ---------------- GEMM: A[M][K] bf16 row-major, Bt[N][K] bf16 (B transposed)
// MODE 0: out bf16 = acc + bias
// MODE 1: GEGLU: obf[r][c] = obf[r][c] * gelu(acc + bias)
// MODE 2: out f32 = acc + bias + resid
// MODE 3: vt store (kv-permuted within 64-granule to match attn P layout)
template<int MODE>
__global__ __launch_bounds__(256, 2)
void gemm_k(const u16* __restrict__ A, const u16* __restrict__ Bt,
            int M, int N, int K,
            const float* __restrict__ bias, const float* __restrict__ resid,
            u16* __restrict__ obf, float* __restrict__ of32,
            int seq, int vstride)
{
  __shared__ __align__(16) u16 As[128 * 32];
  __shared__ __align__(16) u16 Bs[128 * 32];
  const int tid = threadIdx.x;
  const int lane = tid & 63, wave = tid >> 6;
  const int wr = wave >> 1, wc = wave & 1;
  const int g = lane >> 4, r16 = lane & 15;
  const int m0 = blockIdx.x * 128, n0 = blockIdx.y * 128;

  f32x4 acc[4][4] = {};

  const int srow = tid >> 2;
  const int scph = tid & 3;

  for (int kt = 0; kt < K; kt += 32) {
    __syncthreads();
#pragma unroll
    for (int is = 0; is < 2; ++is) {
      int r = srow + is * 64;
      int clog = scph ^ ((r >> 1) & 3);
      int ar = m0 + r; if (ar > M - 1) ar = M - 1;
      gload16(A + (size_t)ar * K + kt + clog * 8, &As[(r * 4 + scph) * 8]);
    }
#pragma unroll
    for (int is = 0; is < 2; ++is) {
      int r = srow + is * 64;
      int clog = scph ^ ((r >> 1) & 3);
      gload16(Bt + (size_t)(n0 + r) * K + kt + clog * 8, &Bs[(r * 4 + scph) * 8]);
    }
    asm volatile("s_waitcnt vmcnt(0)" ::: "memory");
    __syncthreads();

    bf16x8 af[4], bfr[4];
#pragma unroll
    for (int mi = 0; mi < 4; ++mi) {
      int r = wr * 64 + mi * 16 + r16;
      int cph = g ^ ((r >> 1) & 3);
      af[mi] = *(const bf16x8*)&As[(r * 4 + cph) * 8];
    }
#pragma unroll
    for (int ni = 0; ni < 4; ++ni) {
      int r = wc * 64 + ni * 16 + r16;
      int cph = g ^ ((r >> 1) & 3);
      bfr[ni] = *(const bf16x8*)&Bs[(r * 4 + cph) * 8];
    }
#pragma unroll
    for (int mi = 0; mi < 4; ++mi)
#pragma unroll
      for (int ni = 0; ni < 4; ++ni)
        acc[mi][ni] = mfma16(af[mi], bfr[ni], acc[mi][ni]);
  }

#pragma unroll
  for (int ni = 0; ni < 4; ++ni) {
    int col = n0 + wc * 64 + ni * 16 + r16;
    float bv = bias ? bias[col] : 0.0f;
#pragma unroll
    for (int mi = 0; mi < 4; ++mi) {
      f32x4 c = acc[mi][ni];
#pragma unroll
      for (int rg = 0; rg < 4; ++rg) {
        int row = m0 + wr * 64 + mi * 16 + g * 4 + rg;
        if (row < M) {
          float v = c[rg] + bv;
          if constexpr (MODE == 0) {
            obf[(size_t)row * N + col] = f2bf(v);
          } else if constexpr (MODE == 1) {
            size_t o = (size_t)row * N + col;
            float a = bf2f(obf[o]);
            float gl = 0.5f * v * (1.0f + erff(v * 0.70710678f));
            obf[o] = f2bf(a * gl);
          } else if constexpr (MODE == 2) {
            size_t o = (size_t)row * N + col;
            of32[o] = v + resid[o];
          } else {
            int b = row / seq, srow_ = row - b * seq;
            int jg = srow_ >> 6, j = srow_ & 63;
            int pos = jg * 64 + ((j & 15) << 2) + (j >> 4);
            obf[((size_t)b * HEADS * DHEAD + col) * vstride + pos] = f2bf(v);
          }
        }
      }
    }
  }
}

// ---------------- flash attention v3 (defer-max + lane-local li + packed P)
__global__ __launch_bounds__(256)
void attn_k(const u16* __restrict__ q, const u16* __restrict__ k,
            const u16* __restrict__ vt, u16* __restrict__ o,
            int kvlen, int seqk, int vstride)
{
  __shared__ __align__(16) u16 Ks[2][64 * 64];
  __shared__ __align__(16) u16 Vs[2][64 * 64];
  __shared__ __align__(16) u16 Ps[4][32 * 72];
  const int tid = threadIdx.x, lane = tid & 63, wave = tid >> 6;
  const int g = lane >> 4, r16 = lane & 15;
  const int bh = blockIdx.y;
  const int b = bh >> 4, h = bh & 15;
  const int q0 = blockIdx.x * 128 + wave * 32;
  const float C = 0.18033688f;   // log2(e)/8

  bf16x8 aq[2][2];
#pragma unroll
  for (int qs = 0; qs < 2; ++qs) {
    const size_t qoff = (size_t)(b * SEQ + q0 + qs * 16 + r16) * DIMN + h * DHEAD;
#pragma unroll
    for (int kc = 0; kc < 2; ++kc)
      aq[qs][kc] = *(const bf16x8*)&q[qoff + kc * 32 + g * 8];
  }

  f32x4 oacc[2][4] = {};
  float mi[2][4], li[2][4];
#pragma unroll
  for (int qs = 0; qs < 2; ++qs)
#pragma unroll
    for (int rg = 0; rg < 4; ++rg) { mi[qs][rg] = -3e38f; li[qs][rg] = 0.f; }

  const size_t vtbase = (size_t)(b * HEADS + h) * DHEAD * vstride;
  const size_t kbase  = (size_t)b * seqk * DIMN + h * DHEAD;
  const int nkv = (kvlen + 63) >> 6;

  auto stage = [&](int buf, int kv0) {
#pragma unroll
    for (int i = 0; i < 2; ++i) {
      const int c = tid + i * 256;
      const int row = c >> 3, ch = c & 7;
      const int chs = ch ^ (row & 7);
      int kr = kv0 + row; if (kr > kvlen - 1) kr = kvlen - 1;
      gload16(k + kbase + (size_t)kr * DIMN + chs * 8, &Ks[buf][c * 8]);
    }
#pragma unroll
    for (int i = 0; i < 2; ++i) {
      const int c = tid + i * 256;
      const int row = c >> 3, ch = c & 7;
      const int chs = ch ^ (row & 7);
      gload16(vt + vtbase + (size_t)row * vstride + kv0 + chs * 8, &Vs[buf][c * 8]);
    }
  };

  stage(0, 0);
  asm volatile("s_waitcnt vmcnt(0)" ::: "memory");
  __syncthreads();

  for (int kvb = 0; kvb < nkv; ++kvb) {
    const int kv0 = kvb * 64;
    const int cur = kvb & 1;
    if (kvb + 1 < nkv) stage(cur ^ 1, kv0 + 64);

    // ---- QK^T: 16 MFMA
    f32x4 sa[2][4];
#pragma unroll
    for (int qs = 0; qs < 2; ++qs)
#pragma unroll
      for (int st = 0; st < 4; ++st) sa[qs][st] = (f32x4){0.f, 0.f, 0.f, 0.f};
    __builtin_amdgcn_s_setprio(1);
#pragma unroll
    for (int st = 0; st < 4; ++st) {
      const int kvr = st * 16 + r16;
#pragma unroll
      for (int kc = 0; kc < 2; ++kc) {
        const int chs = (kc * 4 + g) ^ (kvr & 7);
        const bf16x8 kf = *(const bf16x8*)&Ks[cur][kvr * 64 + chs * 8];
        sa[0][st] = mfma16(aq[0][kc], kf, sa[0][st]);
        sa[1][st] = mfma16(aq[1][kc], kf, sa[1][st]);
      }
    }
    __builtin_amdgcn_s_setprio(0);

    // ---- tail mask (cross-attn last tile only)
    if (kv0 + 64 > kvlen) {
#pragma unroll
      for (int st = 0; st < 4; ++st)
        if (kv0 + st * 16 + r16 >= kvlen) {
#pragma unroll
          for (int qs = 0; qs < 2; ++qs)
#pragma unroll
            for (int rg = 0; rg < 4; ++rg) sa[qs][st][rg] = -3e38f;
        }
    }

    // ---- defer-max check
    float bad = 0.f;
    float m4v[2][4];
#pragma unroll
    for (int qs = 0; qs < 2; ++qs)
#pragma unroll
      for (int rg = 0; rg < 4; ++rg) {
        float m4 = fmaxf(fmaxf(sa[qs][0][rg], sa[qs][1][rg]),
                         fmaxf(sa[qs][2][rg], sa[qs][3][rg]));
        m4v[qs][rg] = m4;
        bad = fmaxf(bad, m4 - mi[qs][rg]);
      }
    if (__any(bad > 16.0f)) {   // slow path: refresh maxes + rescale
#pragma unroll
      for (int qs = 0; qs < 2; ++qs)
#pragma unroll
        for (int rg = 0; rg < 4; ++rg) {
          float mx = m4v[qs][rg];
#pragma unroll
          for (int off = 1; off < 16; off <<= 1) mx = fmaxf(mx, __shfl_xor(mx, off));
          const float nm = fmaxf(mi[qs][rg], mx);
          const float corr = __builtin_amdgcn_exp2f((mi[qs][rg] - nm) * C);
          mi[qs][rg] = nm;
          li[qs][rg] *= corr;
#pragma unroll
          for (int ds = 0; ds < 4; ++ds) oacc[qs][ds][rg] *= corr;
        }
    }

    // ---- P = exp, lane-local li accumulate, packed bf16 store
#pragma unroll
    for (int qs = 0; qs < 2; ++qs) {
#pragma unroll
      for (int rg = 0; rg < 4; ++rg) {
        const float mc = mi[qs][rg] * C;
        const float p0 = __builtin_amdgcn_exp2f(__builtin_fmaf(sa[qs][0][rg], C, -mc));
        const float p1 = __builtin_amdgcn_exp2f(__builtin_fmaf(sa[qs][1][rg], C, -mc));
        const float p2 = __builtin_amdgcn_exp2f(__builtin_fmaf(sa[qs][2][rg], C, -mc));
        const float p3 = __builtin_amdgcn_exp2f(__builtin_fmaf(sa[qs][3][rg], C, -mc));
        li[qs][rg] += (p0 + p1) + (p2 + p3);
        unsigned lo, hi;
        asm("v_cvt_pk_bf16_f32 %0, %1, %2" : "=v"(lo) : "v"(p0), "v"(p1));
        asm("v_cvt_pk_bf16_f32 %0, %1, %2" : "=v"(hi) : "v"(p2), "v"(p3));
        const int prow = qs * 16 + g * 4 + rg;
        uint2 pk; pk.x = lo; pk.y = hi;
        *(uint2*)&Ps[wave][prow * 72 + r16 * 4] = pk;
      }
    }

    // ---- PV: 16 MFMA
    __builtin_amdgcn_s_setprio(1);
#pragma unroll
    for (int kc = 0; kc < 2; ++kc) {
      const bf16x8 pa0 = *(const bf16x8*)&Ps[wave][(r16)      * 72 + kc * 32 + g * 8];
      const bf16x8 pa1 = *(const bf16x8*)&Ps[wave][(16 + r16) * 72 + kc * 32 + g * 8];
#pragma unroll
      for (int ds = 0; ds < 4; ++ds) {
        const int dr = ds * 16 + r16;
        const int chs = (kc * 4 + g) ^ (dr & 7);
        const bf16x8 vf = *(const bf16x8*)&Vs[cur][dr * 64 + chs * 8];
        oacc[0][ds] = mfma16(pa0, vf, oacc[0][ds]);
        oacc[1][ds] = mfma16(pa1, vf, oacc[1][ds]);
      }
    }
    __builtin_amdgcn_s_setprio(0);

    asm volatile("s_waitcnt vmcnt(0)" ::: "memory");
    __syncthreads();
  }

  // final cross-lane li reduction (once)
#pragma unroll
  for (int qs = 0; qs < 2; ++qs)
#pragma unroll
    for (int rg = 0; rg < 4; ++rg) {
      float s = li[qs][rg];
#pragma unroll
      for (int off = 1; off < 16; off <<= 1) s += __shfl_xor(s, off);
      li[qs][rg] = s;
    }

#pragma unroll
  for (int qs = 0; qs < 2; ++qs)
#pragma unroll
    for (int rg = 0; rg < 4; ++rg) {
      const float inv = 1.0f / li[qs][rg];
      const int row = q0 + qs * 16 + g * 4 + rg;
      const size_t base = (size_t)(b * SEQ + row) * DIMN + h * DHEAD;
#pragma unroll
      for (int ds = 0; ds < 4; ++ds)
        o[base + ds * 16 + r16] = f2bf(oacc[qs][ds][rg] * inv);
    }
}

extern "C" void kernel_launch(void* const* d_in, const int* in_sizes, int n_in,
                              void* d_out, int out_size, void* d_ws, size_t ws_size,
                              hipStream_t stream)
{
  const float* x   = (const float*)d_in[0];
  const float* ctx = (const float*)d_in[1];
  const float* Wq1 = (const float*)d_in[2];
  const float* Wk1 = (const float*)d_in[3];
  const float* Wv1 = (const float*)d_in[4];
  const float* Wo1 = (const float*)d_in[5];
  const float* bo1 = (const float*)d_in[6];
  const float* Wq2 = (const float*)d_in[7];
  const float* Wk2 = (const float*)d_in[8];
  const float* Wv2 = (const float*)d_in[9];
  const float* Wo2 = (const float*)d_in[10];
  const float* bo2 = (const float*)d_in[11];
  const float* Wp  = (const float*)d_in[12];
  const float* bp  = (const float*)d_in[13];
  const float* W2  = (const float*)d_in[14];
  const float* b2  = (const float*)d_in[15];
  const float* g1  = (const float*)d_in[16];
  const float* be1 = (const float*)d_in[17];
  const float* g2  = (const float*)d_in[18];
  const float* be2 = (const float*)d_in[19];
  const float* g3  = (const float*)d_in[20];
  const float* be3 = (const float*)d_in[21];

  char* ws = (char*)d_ws;
  size_t off = 0;
  auto alloc = [&](size_t bytes) -> void* {
    void* p = ws + off;
    off += (bytes + 255) & ~(size_t)255;
    return p;
  };

  u16* WqT1 = (u16*)alloc((size_t)1024 * 1024 * 2);
  u16* WkT1 = (u16*)alloc((size_t)1024 * 1024 * 2);
  u16* WvT1 = (u16*)alloc((size_t)1024 * 1024 * 2);
  u16* WoT1 = (u16*)alloc((size_t)1024 * 1024 * 2);
  u16* WqT2 = (u16*)alloc((size_t)1024 * 1024 * 2);
  u16* WkT2 = (u16*)alloc((size_t)1024 * 768 * 2);
  u16* WvT2 = (u16*)alloc((size_t)1024 * 768 * 2);
  u16* WoT2 = (u16*)alloc((size_t)1024 * 1024 * 2);
  u16* WpT  = (u16*)alloc((size_t)8192 * 1024 * 2);
  u16* W2T  = (u16*)alloc((size_t)1024 * 4096 * 2);
  float* x1f = (float*)alloc((size_t)NTOK * DIMN * 4);
  float* x2f = (float*)alloc((size_t)NTOK * DIMN * 4);
  u16* ctxb = (u16*)alloc((size_t)CTOK * CTXD * 2);
  u16* k2b  = (u16*)alloc((size_t)CTOK * DIMN * 2);
  u16* vt2b = (u16*)alloc((size_t)2 * HEADS * DHEAD * 128 * 2);
  u16* hb   = (u16*)alloc((size_t)NTOK * DIMN * 2);
  u16* qb   = (u16*)alloc((size_t)NTOK * DIMN * 2);
  u16* kb   = (u16*)alloc((size_t)NTOK * DIMN * 2);
  u16* vtb  = (u16*)alloc((size_t)NTOK * DIMN * 2);
  u16* ab   = (u16*)alloc((size_t)NTOK * DIMN * 2);
  u16* ub   = qb; // reuse qb..ab region (32MB) for FF intermediate [4096][4096]

  dim3 blk(256);

  wconv_k<<<dim3(16, 16), blk, 0, stream>>>(Wq1, WqT1, 1024, 1024);
  wconv_k<<<dim3(16, 16), blk, 0, stream>>>(Wk1, WkT1, 1024, 1024);
  wconv_k<<<dim3(16, 16), blk, 0, stream>>>(Wv1, WvT1, 1024, 1024);
  wconv_k<<<dim3(16, 16), blk, 0, stream>>>(Wo1, WoT1, 1024, 1024);
  wconv_k<<<dim3(16, 16), blk, 0, stream>>>(Wq2, WqT2, 1024, 1024);
  wconv_k<<<dim3(16, 12), blk, 0, stream>>>(Wk2, WkT2, 768, 1024);
  wconv_k<<<dim3(16, 12), blk, 0, stream>>>(Wv2, WvT2, 768, 1024);
  wconv_k<<<dim3(16, 16), blk, 0, stream>>>(Wo2, WoT2, 1024, 1024);
  wconv_k<<<dim3(128, 16), blk, 0, stream>>>(Wp, WpT, 1024, 8192);
  wconv_k<<<dim3(16, 64), blk, 0, stream>>>(W2, W2T, 4096, 1024);
  cconv_k<<<dim3((CTOK * CTXD + 255) / 256), blk, 0, stream>>>(ctx, ctxb, CTOK * CTXD);

  // ---- self attention block
  ln_k<<<NTOK, 256, 0, stream>>>(x, g1, be1, hb);
  gemm_k<0><<<dim3(32, 8), blk, 0, stream>>>(hb, WqT1, NTOK, 1024, 1024, nullptr, nullptr, qb, nullptr, 0, 0);
  gemm_k<0><<<dim3(32, 8), blk, 0, stream>>>(hb, WkT1, NTOK, 1024, 1024, nullptr, nullptr, kb, nullptr, 0, 0);
  gemm_k<3><<<dim3(32, 8), blk, 0, stream>>>(hb, WvT1, NTOK, 1024, 1024, nullptr, nullptr, vtb, nullptr, SEQ, SEQ);
  attn_k<<<dim3(16, 32), blk, 0, stream>>>(qb, kb, vtb, ab, SEQ, SEQ, SEQ);
  gemm_k<2><<<dim3(32, 8), blk, 0, stream>>>(ab, WoT1, NTOK, 1024, 1024, bo1, x, nullptr, x1f, 0, 0);

  // ---- cross attention block
  ln_k<<<NTOK, 256, 0, stream>>>(x1f, g2, be2, hb);
  gemm_k<0><<<dim3(32, 8), blk, 0, stream>>>(hb, WqT2, NTOK, 1024, 1024, nullptr, nullptr, qb, nullptr, 0, 0);
  gemm_k<0><<<dim3(2, 8), blk, 0, stream>>>(ctxb, WkT2, CTOK, 1024, 768, nullptr, nullptr, k2b, nullptr, 0, 0);
  gemm_k<3><<<dim3(2, 8), blk, 0, stream>>>(ctxb, WvT2, CTOK, 1024, 768, nullptr, nullptr, vt2b, nullptr, NCTX, 128);
  attn_k<<<dim3(16, 32), blk, 0, stream>>>(qb, k2b, vt2b, ab, NCTX, NCTX, 128);
  gemm_k<2><<<dim3(32, 8), blk, 0, stream>>>(ab, WoT2, NTOK, 1024, 1024, bo2, x1f, nullptr, x2f, 0, 0);

  // ---- GEGLU FF block
  ln_k<<<NTOK, 256, 0, stream>>>(x2f, g3, be3, hb);
  gemm_k<0><<<dim3(32, 32), blk, 0, stream>>>(hb, WpT, NTOK, FFH, 1024, bp, nullptr, ub, nullptr, 0, 0);
  gemm_k<1><<<dim3(32, 32), blk, 0, stream>>>(hb, WpT + (size_t)4096 * 1024, NTOK, FFH, 1024, bp + 4096, nullptr, ub, nullptr, 0, 0);
  gemm_k<2><<<dim3(32, 8), blk, 0, stream>>>(ub, W2T, NTOK, 1024, 4096, b2, x2f, nullptr, (float*)d_out, 0, 0);

  (void)in_sizes; (void)n_in; (void)out_size; (void)ws_size;
}

// Round 4
// 482.863 us; speedup vs baseline: 1.4225x; 1.2160x over previous
//
#include <hip/hip_runtime.h>
#include <hip/hip_bf16.h>
#include <math.h>

#define DIMN   1024
#define HEADS  16
#define DHEAD  64
#define CTXD   768
#define FFH    4096
#define NTOK   4096
#define SEQ    2048
#define NCTX   77
#define CTOK   154

typedef unsigned short u16;
typedef __bf16 bf16x8 __attribute__((ext_vector_type(8)));
typedef float  f32x4  __attribute__((ext_vector_type(4)));

__device__ __forceinline__ u16 f2bf(float f) {
  union { float f; unsigned u; } c; c.f = f;
  unsigned r = c.u + 0x7FFFu + ((c.u >> 16) & 1u);
  return (u16)(r >> 16);
}
__device__ __forceinline__ float bf2f(u16 h) {
  union { unsigned u; float f; } c; c.u = ((unsigned)h) << 16; return c.f;
}

__device__ __forceinline__ void gload16(const void* g, void* l) {
  __builtin_amdgcn_global_load_lds(
      (__attribute__((address_space(1))) void*)(void*)(g),
      (__attribute__((address_space(3))) void*)(l), 16, 0, 0);
}

__device__ __forceinline__ f32x4 mfma16(bf16x8 a, bf16x8 b, f32x4 c) {
  return __builtin_amdgcn_mfma_f32_16x16x32_bf16(a, b, c, 0, 0, 0);
}

// ---------------- weight convert + transpose:  W[K][N] f32 -> WT[N][K] bf16
__global__ __launch_bounds__(256)
void wconv_k(const float* __restrict__ W, u16* __restrict__ WT, int K, int N)
{
  __shared__ u16 t[64][65];
  int n0 = blockIdx.x * 64, k0 = blockIdx.y * 64;
  int tid = threadIdx.x;
  int rr = tid >> 4, cc = tid & 15;
#pragma unroll
  for (int i = 0; i < 4; ++i) {
    int kr = rr + i * 16;
    const float4 v = *(const float4*)&W[(size_t)(k0 + kr) * N + n0 + cc * 4];
    t[kr][cc*4+0] = f2bf(v.x); t[kr][cc*4+1] = f2bf(v.y);
    t[kr][cc*4+2] = f2bf(v.z); t[kr][cc*4+3] = f2bf(v.w);
  }
  __syncthreads();
#pragma unroll
  for (int i = 0; i < 4; ++i) {
    int nr = rr + i * 16;
    int r0 = cc * 4;
    ushort4 o;
    o.x = t[r0+0][nr]; o.y = t[r0+1][nr]; o.z = t[r0+2][nr]; o.w = t[r0+3][nr];
    *(ushort4*)&WT[(size_t)(n0 + nr) * K + k0 + r0] = o;
  }
}

// ---------------- f32 -> bf16 elementwise (context)
__global__ void cconv_k(const float* __restrict__ c, u16* __restrict__ o, int n)
{
  int i = blockIdx.x * 256 + threadIdx.x;
  if (i < n) o[i] = f2bf(c[i]);
}

// ---------------- LayerNorm: f32 row[1024] -> bf16
__global__ __launch_bounds__(256)
void ln_k(const float* __restrict__ x, const float* __restrict__ gm,
          const float* __restrict__ bt, u16* __restrict__ o)
{
  int row = blockIdx.x;
  int tid = threadIdx.x;
  const float4 v = *(const float4*)&x[(size_t)row * DIMN + tid * 4];
  float s = v.x + v.y + v.z + v.w;
  float q = v.x*v.x + v.y*v.y + v.z*v.z + v.w*v.w;
#pragma unroll
  for (int off = 32; off; off >>= 1) { s += __shfl_xor(s, off); q += __shfl_xor(q, off); }
  __shared__ float ss[4], qq[4];
  int wave = tid >> 6;
  if ((tid & 63) == 0) { ss[wave] = s; qq[wave] = q; }
  __syncthreads();
  s = ss[0] + ss[1] + ss[2] + ss[3];
  q = qq[0] + qq[1] + qq[2] + qq[3];
  float mu = s * (1.0f / DIMN);
  float var = q * (1.0f / DIMN) - mu * mu;
  float rs = rsqrtf(var + 1e-5f);
  const float4 gv = *(const float4*)&gm[tid * 4];
  const float4 bv = *(const float4*)&bt[tid * 4];
  ushort4 r;
  r.x = f2bf((v.x - mu) * rs * gv.x + bv.x);
  r.y = f2bf((v.y - mu) * rs * gv.y + bv.y);
  r.z = f2bf((v.z - mu) * rs * gv.z + bv.z);
  r.w = f2bf((v.w - mu) * rs * gv.w + bv.w);
  *(ushort4*)&o[(size_t)row * DIMN + tid * 4] = r;
}

// ---------------- GEMM v2: 512 threads, 8 waves (32x64 wave tile), 2-phase dbuf
// A[M][K] bf16 row-major, Bt[N][K] bf16
// MODE 0: out bf16 = acc + bias
// MODE 2: out f32 = acc + bias + resid
// MODE 3: vt store (kv-permuted within 64-granule to match attn P layout)
template<int MODE>
__global__ __launch_bounds__(512, 4)
void gemm_k(const u16* __restrict__ A, const u16* __restrict__ Bt,
            int M, int N, int K,
            const float* __restrict__ bias, const float* __restrict__ resid,
            u16* __restrict__ obf, float* __restrict__ of32,
            int seq, int vstride)
{
  __shared__ __align__(16) u16 As[2][128 * 32];
  __shared__ __align__(16) u16 Bs[2][128 * 32];
  const int tid = threadIdx.x;
  const int lane = tid & 63, wave = tid >> 6;
  const int wr = wave >> 1, wc = wave & 1;          // 4 x 2 wave grid
  const int g = lane >> 4, r16 = lane & 15;
  const int m0 = blockIdx.x * 128, n0 = blockIdx.y * 128;

  f32x4 acc[2][4] = {};

  // staging: 512 chunks of 16B per tile -> 1 A chunk + 1 B chunk per thread
  const int srow = tid >> 2;          // 0..127
  const int sch  = tid & 3;           // 0..3
  const int schs = sch ^ ((srow >> 1) & 3);
  const int arow = (m0 + srow > M - 1) ? (M - 1) : (m0 + srow);
  const size_t abase = (size_t)arow * K + schs * 8;
  const size_t bbase = (size_t)(n0 + srow) * K + schs * 8;

  auto stage = [&](int buf, int kt) {
    gload16(A  + abase + kt, &As[buf][tid * 8]);
    gload16(Bt + bbase + kt, &Bs[buf][tid * 8]);
  };

  stage(0, 0);
  asm volatile("s_waitcnt vmcnt(0)" ::: "memory");
  __syncthreads();

  const int nkt = K >> 5;
  for (int t = 0; t < nkt; ++t) {
    const int cur = t & 1;
    if (t + 1 < nkt) stage(cur ^ 1, (t + 1) << 5);

    bf16x8 af[2], bfr[4];
#pragma unroll
    for (int mi = 0; mi < 2; ++mi) {
      int r = wr * 32 + mi * 16 + r16;
      int cph = g ^ ((r >> 1) & 3);
      af[mi] = *(const bf16x8*)&As[cur][(r * 4 + cph) * 8];
    }
#pragma unroll
    for (int ni = 0; ni < 4; ++ni) {
      int r = wc * 64 + ni * 16 + r16;
      int cph = g ^ ((r >> 1) & 3);
      bfr[ni] = *(const bf16x8*)&Bs[cur][(r * 4 + cph) * 8];
    }
    __builtin_amdgcn_s_setprio(1);
#pragma unroll
    for (int mi = 0; mi < 2; ++mi)
#pragma unroll
      for (int ni = 0; ni < 4; ++ni)
        acc[mi][ni] = mfma16(af[mi], bfr[ni], acc[mi][ni]);
    __builtin_amdgcn_s_setprio(0);

    asm volatile("s_waitcnt vmcnt(0)" ::: "memory");
    __syncthreads();
  }

#pragma unroll
  for (int ni = 0; ni < 4; ++ni) {
    int col = n0 + wc * 64 + ni * 16 + r16;
    float bv = bias ? bias[col] : 0.0f;
#pragma unroll
    for (int mi = 0; mi < 2; ++mi) {
      f32x4 c = acc[mi][ni];
#pragma unroll
      for (int rg = 0; rg < 4; ++rg) {
        int row = m0 + wr * 32 + mi * 16 + g * 4 + rg;
        if (row < M) {
          float v = c[rg] + bv;
          if constexpr (MODE == 0) {
            obf[(size_t)row * N + col] = f2bf(v);
          } else if constexpr (MODE == 2) {
            size_t o = (size_t)row * N + col;
            of32[o] = v + resid[o];
          } else {
            int b = row / seq, srow_ = row - b * seq;
            int jg = srow_ >> 6, j = srow_ & 63;
            int pos = jg * 64 + ((j & 15) << 2) + (j >> 4);
            obf[((size_t)b * HEADS * DHEAD + col) * vstride + pos] = f2bf(v);
          }
        }
      }
    }
  }
}

// ---------------- fused GEGLU GEMM: out = (A@B1 + ba) * gelu(A@B2 + bg)
// A[M][1024], B1t/B2t[N][1024]; out bf16 [M][N]
__global__ __launch_bounds__(512, 2)
void geglu_k(const u16* __restrict__ A, const u16* __restrict__ B1t,
             const u16* __restrict__ B2t,
             const float* __restrict__ ba, const float* __restrict__ bg,
             u16* __restrict__ out, int M, int N)
{
  __shared__ __align__(16) u16 As[2][128 * 32];
  __shared__ __align__(16) u16 B1s[2][128 * 32];
  __shared__ __align__(16) u16 B2s[2][128 * 32];
  const int tid = threadIdx.x;
  const int lane = tid & 63, wave = tid >> 6;
  const int wr = wave >> 1, wc = wave & 1;
  const int g = lane >> 4, r16 = lane & 15;
  const int m0 = blockIdx.x * 128, n0 = blockIdx.y * 128;
  const int K = 1024;

  f32x4 acca[2][4] = {}, accg[2][4] = {};

  const int srow = tid >> 2;
  const int sch  = tid & 3;
  const int schs = sch ^ ((srow >> 1) & 3);
  const size_t abase = (size_t)(m0 + srow) * K + schs * 8;
  const size_t bbase = (size_t)(n0 + srow) * K + schs * 8;

  auto stage = [&](int buf, int kt) {
    gload16(A   + abase + kt, &As[buf][tid * 8]);
    gload16(B1t + bbase + kt, &B1s[buf][tid * 8]);
    gload16(B2t + bbase + kt, &B2s[buf][tid * 8]);
  };

  stage(0, 0);
  asm volatile("s_waitcnt vmcnt(0)" ::: "memory");
  __syncthreads();

  const int nkt = K >> 5;
  for (int t = 0; t < nkt; ++t) {
    const int cur = t & 1;
    if (t + 1 < nkt) stage(cur ^ 1, (t + 1) << 5);

    bf16x8 af[2], b1f[4], b2f[4];
#pragma unroll
    for (int mi = 0; mi < 2; ++mi) {
      int r = wr * 32 + mi * 16 + r16;
      int cph = g ^ ((r >> 1) & 3);
      af[mi] = *(const bf16x8*)&As[cur][(r * 4 + cph) * 8];
    }
#pragma unroll
    for (int ni = 0; ni < 4; ++ni) {
      int r = wc * 64 + ni * 16 + r16;
      int cph = g ^ ((r >> 1) & 3);
      b1f[ni] = *(const bf16x8*)&B1s[cur][(r * 4 + cph) * 8];
      b2f[ni] = *(const bf16x8*)&B2s[cur][(r * 4 + cph) * 8];
    }
    __builtin_amdgcn_s_setprio(1);
#pragma unroll
    for (int mi = 0; mi < 2; ++mi)
#pragma unroll
      for (int ni = 0; ni < 4; ++ni) {
        acca[mi][ni] = mfma16(af[mi], b1f[ni], acca[mi][ni]);
        accg[mi][ni] = mfma16(af[mi], b2f[ni], accg[mi][ni]);
      }
    __builtin_amdgcn_s_setprio(0);

    asm volatile("s_waitcnt vmcnt(0)" ::: "memory");
    __syncthreads();
  }

#pragma unroll
  for (int ni = 0; ni < 4; ++ni) {
    int col = n0 + wc * 64 + ni * 16 + r16;
    float bva = ba[col], bvg = bg[col];
#pragma unroll
    for (int mi = 0; mi < 2; ++mi) {
#pragma unroll
      for (int rg = 0; rg < 4; ++rg) {
        int row = m0 + wr * 32 + mi * 16 + g * 4 + rg;
        float a  = acca[mi][ni][rg] + bva;
        float gt = accg[mi][ni][rg] + bvg;
        float gl = 0.5f * gt * (1.0f + erff(gt * 0.70710678f));
        out[(size_t)row * N + col] = f2bf(a * gl);
      }
    }
  }
}

// ---------------- flash attention v3 (defer-max + lane-local li + packed P)
__global__ __launch_bounds__(256)
void attn_k(const u16* __restrict__ q, const u16* __restrict__ k,
            const u16* __restrict__ vt, u16* __restrict__ o,
            int kvlen, int seqk, int vstride)
{
  __shared__ __align__(16) u16 Ks[2][64 * 64];
  __shared__ __align__(16) u16 Vs[2][64 * 64];
  __shared__ __align__(16) u16 Ps[4][32 * 72];
  const int tid = threadIdx.x, lane = tid & 63, wave = tid >> 6;
  const int g = lane >> 4, r16 = lane & 15;
  const int bh = blockIdx.y;
  const int b = bh >> 4, h = bh & 15;
  const int q0 = blockIdx.x * 128 + wave * 32;
  const float C = 0.18033688f;   // log2(e)/8

  bf16x8 aq[2][2];
#pragma unroll
  for (int qs = 0; qs < 2; ++qs) {
    const size_t qoff = (size_t)(b * SEQ + q0 + qs * 16 + r16) * DIMN + h * DHEAD;
#pragma unroll
    for (int kc = 0; kc < 2; ++kc)
      aq[qs][kc] = *(const bf16x8*)&q[qoff + kc * 32 + g * 8];
  }

  f32x4 oacc[2][4] = {};
  float mi[2][4], li[2][4];
#pragma unroll
  for (int qs = 0; qs < 2; ++qs)
#pragma unroll
    for (int rg = 0; rg < 4; ++rg) { mi[qs][rg] = -3e38f; li[qs][rg] = 0.f; }

  const size_t vtbase = (size_t)(b * HEADS + h) * DHEAD * vstride;
  const size_t kbase  = (size_t)b * seqk * DIMN + h * DHEAD;
  const int nkv = (kvlen + 63) >> 6;

  auto stage = [&](int buf, int kv0) {
#pragma unroll
    for (int i = 0; i < 2; ++i) {
      const int c = tid + i * 256;
      const int row = c >> 3, ch = c & 7;
      const int chs = ch ^ (row & 7);
      int kr = kv0 + row; if (kr > kvlen - 1) kr = kvlen - 1;
      gload16(k + kbase + (size_t)kr * DIMN + chs * 8, &Ks[buf][c * 8]);
    }
#pragma unroll
    for (int i = 0; i < 2; ++i) {
      const int c = tid + i * 256;
      const int row = c >> 3, ch = c & 7;
      const int chs = ch ^ (row & 7);
      gload16(vt + vtbase + (size_t)row * vstride + kv0 + chs * 8, &Vs[buf][c * 8]);
    }
  };

  stage(0, 0);
  asm volatile("s_waitcnt vmcnt(0)" ::: "memory");
  __syncthreads();

  for (int kvb = 0; kvb < nkv; ++kvb) {
    const int kv0 = kvb * 64;
    const int cur = kvb & 1;
    if (kvb + 1 < nkv) stage(cur ^ 1, kv0 + 64);

    // ---- QK^T: 16 MFMA
    f32x4 sa[2][4];
#pragma unroll
    for (int qs = 0; qs < 2; ++qs)
#pragma unroll
      for (int st = 0; st < 4; ++st) sa[qs][st] = (f32x4){0.f, 0.f, 0.f, 0.f};
    __builtin_amdgcn_s_setprio(1);
#pragma unroll
    for (int st = 0; st < 4; ++st) {
      const int kvr = st * 16 + r16;
#pragma unroll
      for (int kc = 0; kc < 2; ++kc) {
        const int chs = (kc * 4 + g) ^ (kvr & 7);
        const bf16x8 kf = *(const bf16x8*)&Ks[cur][kvr * 64 + chs * 8];
        sa[0][st] = mfma16(aq[0][kc], kf, sa[0][st]);
        sa[1][st] = mfma16(aq[1][kc], kf, sa[1][st]);
      }
    }
    __builtin_amdgcn_s_setprio(0);

    // ---- tail mask (cross-attn last tile only)
    if (kv0 + 64 > kvlen) {
#pragma unroll
      for (int st = 0; st < 4; ++st)
        if (kv0 + st * 16 + r16 >= kvlen) {
#pragma unroll
          for (int qs = 0; qs < 2; ++qs)
#pragma unroll
            for (int rg = 0; rg < 4; ++rg) sa[qs][st][rg] = -3e38f;
        }
    }

    // ---- defer-max check
    float bad = 0.f;
    float m4v[2][4];
#pragma unroll
    for (int qs = 0; qs < 2; ++qs)
#pragma unroll
      for (int rg = 0; rg < 4; ++rg) {
        float m4 = fmaxf(fmaxf(sa[qs][0][rg], sa[qs][1][rg]),
                         fmaxf(sa[qs][2][rg], sa[qs][3][rg]));
        m4v[qs][rg] = m4;
        bad = fmaxf(bad, m4 - mi[qs][rg]);
      }
    if (__any(bad > 16.0f)) {   // slow path: refresh maxes + rescale
#pragma unroll
      for (int qs = 0; qs < 2; ++qs)
#pragma unroll
        for (int rg = 0; rg < 4; ++rg) {
          float mx = m4v[qs][rg];
#pragma unroll
          for (int off = 1; off < 16; off <<= 1) mx = fmaxf(mx, __shfl_xor(mx, off));
          const float nm = fmaxf(mi[qs][rg], mx);
          const float corr = __builtin_amdgcn_exp2f((mi[qs][rg] - nm) * C);
          mi[qs][rg] = nm;
          li[qs][rg] *= corr;
#pragma unroll
          for (int ds = 0; ds < 4; ++ds) oacc[qs][ds][rg] *= corr;
        }
    }

    // ---- P = exp, lane-local li accumulate, packed bf16 store
#pragma unroll
    for (int qs = 0; qs < 2; ++qs) {
#pragma unroll
      for (int rg = 0; rg < 4; ++rg) {
        const float mc = mi[qs][rg] * C;
        const float p0 = __builtin_amdgcn_exp2f(__builtin_fmaf(sa[qs][0][rg], C, -mc));
        const float p1 = __builtin_amdgcn_exp2f(__builtin_fmaf(sa[qs][1][rg], C, -mc));
        const float p2 = __builtin_amdgcn_exp2f(__builtin_fmaf(sa[qs][2][rg], C, -mc));
        const float p3 = __builtin_amdgcn_exp2f(__builtin_fmaf(sa[qs][3][rg], C, -mc));
        li[qs][rg] += (p0 + p1) + (p2 + p3);
        unsigned lo, hi;
        asm("v_cvt_pk_bf16_f32 %0, %1, %2" : "=v"(lo) : "v"(p0), "v"(p1));
        asm("v_cvt_pk_bf16_f32 %0, %1, %2" : "=v"(hi) : "v"(p2), "v"(p3));
        const int prow = qs * 16 + g * 4 + rg;
        uint2 pk; pk.x = lo; pk.y = hi;
        *(uint2*)&Ps[wave][prow * 72 + r16 * 4] = pk;
      }
    }

    // ---- PV: 16 MFMA
    __builtin_amdgcn_s_setprio(1);
#pragma unroll
    for (int kc = 0; kc < 2; ++kc) {
      const bf16x8 pa0 = *(const bf16x8*)&Ps[wave][(r16)      * 72 + kc * 32 + g * 8];
      const bf16x8 pa1 = *(const bf16x8*)&Ps[wave][(16 + r16) * 72 + kc * 32 + g * 8];
#pragma unroll
      for (int ds = 0; ds < 4; ++ds) {
        const int dr = ds * 16 + r16;
        const int chs = (kc * 4 + g) ^ (dr & 7);
        const bf16x8 vf = *(const bf16x8*)&Vs[cur][dr * 64 + chs * 8];
        oacc[0][ds] = mfma16(pa0, vf, oacc[0][ds]);
        oacc[1][ds] = mfma16(pa1, vf, oacc[1][ds]);
      }
    }
    __builtin_amdgcn_s_setprio(0);

    asm volatile("s_waitcnt vmcnt(0)" ::: "memory");
    __syncthreads();
  }

  // final cross-lane li reduction (once)
#pragma unroll
  for (int qs = 0; qs < 2; ++qs)
#pragma unroll
    for (int rg = 0; rg < 4; ++rg) {
      float s = li[qs][rg];
#pragma unroll
      for (int off = 1; off < 16; off <<= 1) s += __shfl_xor(s, off);
      li[qs][rg] = s;
    }

#pragma unroll
  for (int qs = 0; qs < 2; ++qs)
#pragma unroll
    for (int rg = 0; rg < 4; ++rg) {
      const float inv = 1.0f / li[qs][rg];
      const int row = q0 + qs * 16 + g * 4 + rg;
      const size_t base = (size_t)(b * SEQ + row) * DIMN + h * DHEAD;
#pragma unroll
      for (int ds = 0; ds < 4; ++ds)
        o[base + ds * 16 + r16] = f2bf(oacc[qs][ds][rg] * inv);
    }
}

extern "C" void kernel_launch(void* const* d_in, const int* in_sizes, int n_in,
                              void* d_out, int out_size, void* d_ws, size_t ws_size,
                              hipStream_t stream)
{
  const float* x   = (const float*)d_in[0];
  const float* ctx = (const float*)d_in[1];
  const float* Wq1 = (const float*)d_in[2];
  const float* Wk1 = (const float*)d_in[3];
  const float* Wv1 = (const float*)d_in[4];
  const float* Wo1 = (const float*)d_in[5];
  const float* bo1 = (const float*)d_in[6];
  const float* Wq2 = (const float*)d_in[7];
  const float* Wk2 = (const float*)d_in[8];
  const float* Wv2 = (const float*)d_in[9];
  const float* Wo2 = (const float*)d_in[10];
  const float* bo2 = (const float*)d_in[11];
  const float* Wp  = (const float*)d_in[12];
  const float* bp  = (const float*)d_in[13];
  const float* W2  = (const float*)d_in[14];
  const float* b2  = (const float*)d_in[15];
  const float* g1  = (const float*)d_in[16];
  const float* be1 = (const float*)d_in[17];
  const float* g2  = (const float*)d_in[18];
  const float* be2 = (const float*)d_in[19];
  const float* g3  = (const float*)d_in[20];
  const float* be3 = (const float*)d_in[21];

  char* ws = (char*)d_ws;
  size_t off = 0;
  auto alloc = [&](size_t bytes) -> void* {
    void* p = ws + off;
    off += (bytes + 255) & ~(size_t)255;
    return p;
  };

  u16* WqT1 = (u16*)alloc((size_t)1024 * 1024 * 2);
  u16* WkT1 = (u16*)alloc((size_t)1024 * 1024 * 2);
  u16* WvT1 = (u16*)alloc((size_t)1024 * 1024 * 2);
  u16* WoT1 = (u16*)alloc((size_t)1024 * 1024 * 2);
  u16* WqT2 = (u16*)alloc((size_t)1024 * 1024 * 2);
  u16* WkT2 = (u16*)alloc((size_t)1024 * 768 * 2);
  u16* WvT2 = (u16*)alloc((size_t)1024 * 768 * 2);
  u16* WoT2 = (u16*)alloc((size_t)1024 * 1024 * 2);
  u16* WpT  = (u16*)alloc((size_t)8192 * 1024 * 2);
  u16* W2T  = (u16*)alloc((size_t)1024 * 4096 * 2);
  float* x1f = (float*)alloc((size_t)NTOK * DIMN * 4);
  float* x2f = (float*)alloc((size_t)NTOK * DIMN * 4);
  u16* ctxb = (u16*)alloc((size_t)CTOK * CTXD * 2);
  u16* k2b  = (u16*)alloc((size_t)CTOK * DIMN * 2);
  u16* vt2b = (u16*)alloc((size_t)2 * HEADS * DHEAD * 128 * 2);
  u16* hb   = (u16*)alloc((size_t)NTOK * DIMN * 2);
  u16* qb   = (u16*)alloc((size_t)NTOK * DIMN * 2);
  u16* kb   = (u16*)alloc((size_t)NTOK * DIMN * 2);
  u16* vtb  = (u16*)alloc((size_t)NTOK * DIMN * 2);
  u16* ab   = (u16*)alloc((size_t)NTOK * DIMN * 2);
  u16* ub   = qb; // reuse qb..ab region (32MB) for FF intermediate [4096][4096]

  dim3 blk(256);
  dim3 blk5(512);

  wconv_k<<<dim3(16, 16), blk, 0, stream>>>(Wq1, WqT1, 1024, 1024);
  wconv_k<<<dim3(16, 16), blk, 0, stream>>>(Wk1, WkT1, 1024, 1024);
  wconv_k<<<dim3(16, 16), blk, 0, stream>>>(Wv1, WvT1, 1024, 1024);
  wconv_k<<<dim3(16, 16), blk, 0, stream>>>(Wo1, WoT1, 1024, 1024);
  wconv_k<<<dim3(16, 16), blk, 0, stream>>>(Wq2, WqT2, 1024, 1024);
  wconv_k<<<dim3(16, 12), blk, 0, stream>>>(Wk2, WkT2, 768, 1024);
  wconv_k<<<dim3(16, 12), blk, 0, stream>>>(Wv2, WvT2, 768, 1024);
  wconv_k<<<dim3(16, 16), blk, 0, stream>>>(Wo2, WoT2, 1024, 1024);
  wconv_k<<<dim3(128, 16), blk, 0, stream>>>(Wp, WpT, 1024, 8192);
  wconv_k<<<dim3(16, 64), blk, 0, stream>>>(W2, W2T, 4096, 1024);
  cconv_k<<<dim3((CTOK * CTXD + 255) / 256), blk, 0, stream>>>(ctx, ctxb, CTOK * CTXD);

  // ---- self attention block
  ln_k<<<NTOK, 256, 0, stream>>>(x, g1, be1, hb);
  gemm_k<0><<<dim3(32, 8), blk5, 0, stream>>>(hb, WqT1, NTOK, 1024, 1024, nullptr, nullptr, qb, nullptr, 0, 0);
  gemm_k<0><<<dim3(32, 8), blk5, 0, stream>>>(hb, WkT1, NTOK, 1024, 1024, nullptr, nullptr, kb, nullptr, 0, 0);
  gemm_k<3><<<dim3(32, 8), blk5, 0, stream>>>(hb, WvT1, NTOK, 1024, 1024, nullptr, nullptr, vtb, nullptr, SEQ, SEQ);
  attn_k<<<dim3(16, 32), blk, 0, stream>>>(qb, kb, vtb, ab, SEQ, SEQ, SEQ);
  gemm_k<2><<<dim3(32, 8), blk5, 0, stream>>>(ab, WoT1, NTOK, 1024, 1024, bo1, x, nullptr, x1f, 0, 0);

  // ---- cross attention block
  ln_k<<<NTOK, 256, 0, stream>>>(x1f, g2, be2, hb);
  gemm_k<0><<<dim3(32, 8), blk5, 0, stream>>>(hb, WqT2, NTOK, 1024, 1024, nullptr, nullptr, qb, nullptr, 0, 0);
  gemm_k<0><<<dim3(2, 8), blk5, 0, stream>>>(ctxb, WkT2, CTOK, 1024, 768, nullptr, nullptr, k2b, nullptr, 0, 0);
  gemm_k<3><<<dim3(2, 8), blk5, 0, stream>>>(ctxb, WvT2, CTOK, 1024, 768, nullptr, nullptr, vt2b, nullptr, NCTX, 128);
  attn_k<<<dim3(16, 32), blk, 0, stream>>>(qb, k2b, vt2b, ab, NCTX, NCTX, 128);
  gemm_k<2><<<dim3(32, 8), blk5, 0, stream>>>(ab, WoT2, NTOK, 1024, 1024, bo2, x1f, nullptr, x2f, 0, 0);

  // ---- GEGLU FF block
  ln_k<<<NTOK, 256, 0, stream>>>(x2f, g3, be3, hb);
  geglu_k<<<dim3(32, 32), blk5, 0, stream>>>(hb, WpT, WpT + (size_t)4096 * 1024, bp, bp + 4096, ub, NTOK, FFH);
  gemm_k<2><<<dim3(32, 8), blk5, 0, stream>>>(ub, W2T, NTOK, 1024, 4096, b2, x2f, nullptr, (float*)d_out, 0, 0);

  (void)in_sizes; (void)n_in; (void)out_size; (void)ws_size;
}

// Round 5
// 432.655 us; speedup vs baseline: 1.5876x; 1.1160x over previous
//
#include <hip/hip_runtime.h>
#include <hip/hip_bf16.h>
#include <math.h>

#define DIMN   1024
#define HEADS  16
#define DHEAD  64
#define CTXD   768
#define FFH    4096
#define NTOK   4096
#define SEQ    2048
#define NCTX   77
#define CTOK   154

typedef unsigned short u16;
typedef __bf16 bf16x8 __attribute__((ext_vector_type(8)));
typedef float  f32x4  __attribute__((ext_vector_type(4)));

__device__ __forceinline__ u16 f2bf(float f) {
  union { float f; unsigned u; } c; c.f = f;
  unsigned r = c.u + 0x7FFFu + ((c.u >> 16) & 1u);
  return (u16)(r >> 16);
}
__device__ __forceinline__ float bf2f(u16 h) {
  union { unsigned u; float f; } c; c.u = ((unsigned)h) << 16; return c.f;
}

__device__ __forceinline__ void gload16(const void* g, void* l) {
  __builtin_amdgcn_global_load_lds(
      (__attribute__((address_space(1))) void*)(void*)(g),
      (__attribute__((address_space(3))) void*)(l), 16, 0, 0);
}

__device__ __forceinline__ f32x4 mfma16(bf16x8 a, bf16x8 b, f32x4 c) {
  return __builtin_amdgcn_mfma_f32_16x16x32_bf16(a, b, c, 0, 0, 0);
}

// ---------------- weight convert + transpose:  W[K][N] f32 -> WT[N][K] bf16
__global__ __launch_bounds__(256)
void wconv_k(const float* __restrict__ W, u16* __restrict__ WT, int K, int N)
{
  __shared__ u16 t[64][65];
  int n0 = blockIdx.x * 64, k0 = blockIdx.y * 64;
  int tid = threadIdx.x;
  int rr = tid >> 4, cc = tid & 15;
#pragma unroll
  for (int i = 0; i < 4; ++i) {
    int kr = rr + i * 16;
    const float4 v = *(const float4*)&W[(size_t)(k0 + kr) * N + n0 + cc * 4];
    t[kr][cc*4+0] = f2bf(v.x); t[kr][cc*4+1] = f2bf(v.y);
    t[kr][cc*4+2] = f2bf(v.z); t[kr][cc*4+3] = f2bf(v.w);
  }
  __syncthreads();
#pragma unroll
  for (int i = 0; i < 4; ++i) {
    int nr = rr + i * 16;
    int r0 = cc * 4;
    ushort4 o;
    o.x = t[r0+0][nr]; o.y = t[r0+1][nr]; o.z = t[r0+2][nr]; o.w = t[r0+3][nr];
    *(ushort4*)&WT[(size_t)(n0 + nr) * K + k0 + r0] = o;
  }
}

// ---------------- f32 -> bf16 elementwise (context)
__global__ void cconv_k(const float* __restrict__ c, u16* __restrict__ o, int n)
{
  int i = blockIdx.x * 256 + threadIdx.x;
  if (i < n) o[i] = f2bf(c[i]);
}

// ---------------- LayerNorm: f32 row[1024] -> bf16
__global__ __launch_bounds__(256)
void ln_k(const float* __restrict__ x, const float* __restrict__ gm,
          const float* __restrict__ bt, u16* __restrict__ o)
{
  int row = blockIdx.x;
  int tid = threadIdx.x;
  const float4 v = *(const float4*)&x[(size_t)row * DIMN + tid * 4];
  float s = v.x + v.y + v.z + v.w;
  float q = v.x*v.x + v.y*v.y + v.z*v.z + v.w*v.w;
#pragma unroll
  for (int off = 32; off; off >>= 1) { s += __shfl_xor(s, off); q += __shfl_xor(q, off); }
  __shared__ float ss[4], qq[4];
  int wave = tid >> 6;
  if ((tid & 63) == 0) { ss[wave] = s; qq[wave] = q; }
  __syncthreads();
  s = ss[0] + ss[1] + ss[2] + ss[3];
  q = qq[0] + qq[1] + qq[2] + qq[3];
  float mu = s * (1.0f / DIMN);
  float var = q * (1.0f / DIMN) - mu * mu;
  float rs = rsqrtf(var + 1e-5f);
  const float4 gv = *(const float4*)&gm[tid * 4];
  const float4 bv = *(const float4*)&bt[tid * 4];
  ushort4 r;
  r.x = f2bf((v.x - mu) * rs * gv.x + bv.x);
  r.y = f2bf((v.y - mu) * rs * gv.y + bv.y);
  r.z = f2bf((v.z - mu) * rs * gv.z + bv.z);
  r.w = f2bf((v.w - mu) * rs * gv.w + bv.w);
  *(ushort4*)&o[(size_t)row * DIMN + tid * 4] = r;
}

// ---------------- GEMM v3: 512 threads, 8 waves, dbuf + counted vmcnt
// A[M][K] bf16 row-major, Bt[N][K] bf16
// MODE 0: out bf16 = acc + bias
// MODE 2: out f32 = acc + bias + resid
// MODE 3: vt store (kv-permuted within 64-granule to match attn P layout)
// MODE 4: QKV fused: colgrp 0->obf (q), 1->ob2 (k), 2->ob3 (vt store)
// MODE 5: KV fused:  colgrp 0->obf (k), 1->ob3 (vt store)
template<int MODE>
__global__ __launch_bounds__(512, 4)
void gemm_k(const u16* __restrict__ A, const u16* __restrict__ Bt,
            int M, int N, int K,
            const float* __restrict__ bias, const float* __restrict__ resid,
            u16* __restrict__ obf, float* __restrict__ of32,
            int seq, int vstride,
            u16* __restrict__ ob2, u16* __restrict__ ob3)
{
  __shared__ __align__(16) u16 As[2][128 * 32];
  __shared__ __align__(16) u16 Bs[2][128 * 32];
  const int tid = threadIdx.x;
  const int lane = tid & 63, wave = tid >> 6;
  const int wr = wave >> 1, wc = wave & 1;          // 4 x 2 wave grid
  const int g = lane >> 4, r16 = lane & 15;
  const int m0 = blockIdx.x * 128, n0 = blockIdx.y * 128;

  f32x4 acc[2][4] = {};

  const int srow = tid >> 2;          // 0..127
  const int sch  = tid & 3;           // 0..3
  const int schs = sch ^ ((srow >> 1) & 3);
  const int arow = (m0 + srow > M - 1) ? (M - 1) : (m0 + srow);
  const size_t abase = (size_t)arow * K + schs * 8;
  const size_t bbase = (size_t)(n0 + srow) * K + schs * 8;

  auto stage = [&](int buf, int kt) {
    gload16(A  + abase + kt, &As[buf][tid * 8]);
    gload16(Bt + bbase + kt, &Bs[buf][tid * 8]);
  };

  stage(0, 0);

  const int nkt = K >> 5;
  for (int t = 0; t < nkt; ++t) {
    const int cur = t & 1;
    if (t + 1 < nkt) {
      stage(cur ^ 1, (t + 1) << 5);
      asm volatile("s_waitcnt vmcnt(2)" ::: "memory");   // stage(t) landed; t+1 in flight
    } else {
      asm volatile("s_waitcnt vmcnt(0)" ::: "memory");
    }
    __builtin_amdgcn_s_barrier();                        // B1

    bf16x8 af[2], bfr[4];
#pragma unroll
    for (int mi = 0; mi < 2; ++mi) {
      int r = wr * 32 + mi * 16 + r16;
      int cph = g ^ ((r >> 1) & 3);
      af[mi] = *(const bf16x8*)&As[cur][(r * 4 + cph) * 8];
    }
#pragma unroll
    for (int ni = 0; ni < 4; ++ni) {
      int r = wc * 64 + ni * 16 + r16;
      int cph = g ^ ((r >> 1) & 3);
      bfr[ni] = *(const bf16x8*)&Bs[cur][(r * 4 + cph) * 8];
    }
    __builtin_amdgcn_s_setprio(1);
#pragma unroll
    for (int mi = 0; mi < 2; ++mi)
#pragma unroll
      for (int ni = 0; ni < 4; ++ni)
        acc[mi][ni] = mfma16(af[mi], bfr[ni], acc[mi][ni]);
    __builtin_amdgcn_s_setprio(0);

    __builtin_amdgcn_s_barrier();                        // B2 (WAR on buffers)
  }

  const int grp = n0 >> 10;           // column group for fused modes
#pragma unroll
  for (int ni = 0; ni < 4; ++ni) {
    int col = n0 + wc * 64 + ni * 16 + r16;
    float bv = 0.0f;
    if constexpr (MODE == 0 || MODE == 2) bv = bias ? bias[col] : 0.0f;
    const int c1 = col & 1023;
#pragma unroll
    for (int mi = 0; mi < 2; ++mi) {
      f32x4 c = acc[mi][ni];
#pragma unroll
      for (int rg = 0; rg < 4; ++rg) {
        int row = m0 + wr * 32 + mi * 16 + g * 4 + rg;
        if (row < M) {
          float v = c[rg] + bv;
          if constexpr (MODE == 0) {
            obf[(size_t)row * N + col] = f2bf(v);
          } else if constexpr (MODE == 2) {
            size_t o = (size_t)row * N + col;
            of32[o] = v + resid[o];
          } else if constexpr (MODE == 3) {
            int b = row / seq, srow_ = row - b * seq;
            int jg = srow_ >> 6, j = srow_ & 63;
            int pos = jg * 64 + ((j & 15) << 2) + (j >> 4);
            obf[((size_t)b * HEADS * DHEAD + c1) * vstride + pos] = f2bf(v);
          } else if constexpr (MODE == 4) {
            if (grp == 0) {
              obf[(size_t)row * 1024 + c1] = f2bf(v);
            } else if (grp == 1) {
              ob2[(size_t)row * 1024 + c1] = f2bf(v);
            } else {
              int b = row / seq, srow_ = row - b * seq;
              int jg = srow_ >> 6, j = srow_ & 63;
              int pos = jg * 64 + ((j & 15) << 2) + (j >> 4);
              ob3[((size_t)b * HEADS * DHEAD + c1) * vstride + pos] = f2bf(v);
            }
          } else {  // MODE 5
            if (grp == 0) {
              obf[(size_t)row * 1024 + c1] = f2bf(v);
            } else {
              int b = row / seq, srow_ = row - b * seq;
              int jg = srow_ >> 6, j = srow_ & 63;
              int pos = jg * 64 + ((j & 15) << 2) + (j >> 4);
              ob3[((size_t)b * HEADS * DHEAD + c1) * vstride + pos] = f2bf(v);
            }
          }
        }
      }
    }
  }
}

// ---------------- fused GEGLU GEMM: out = (A@B1 + ba) * gelu(A@B2 + bg)
__global__ __launch_bounds__(512, 2)
void geglu_k(const u16* __restrict__ A, const u16* __restrict__ B1t,
             const u16* __restrict__ B2t,
             const float* __restrict__ ba, const float* __restrict__ bg,
             u16* __restrict__ out, int M, int N)
{
  __shared__ __align__(16) u16 As[2][128 * 32];
  __shared__ __align__(16) u16 B1s[2][128 * 32];
  __shared__ __align__(16) u16 B2s[2][128 * 32];
  const int tid = threadIdx.x;
  const int lane = tid & 63, wave = tid >> 6;
  const int wr = wave >> 1, wc = wave & 1;
  const int g = lane >> 4, r16 = lane & 15;
  const int m0 = blockIdx.x * 128, n0 = blockIdx.y * 128;
  const int K = 1024;

  f32x4 acca[2][4] = {}, accg[2][4] = {};

  const int srow = tid >> 2;
  const int sch  = tid & 3;
  const int schs = sch ^ ((srow >> 1) & 3);
  const size_t abase = (size_t)(m0 + srow) * K + schs * 8;
  const size_t bbase = (size_t)(n0 + srow) * K + schs * 8;

  auto stage = [&](int buf, int kt) {
    gload16(A   + abase + kt, &As[buf][tid * 8]);
    gload16(B1t + bbase + kt, &B1s[buf][tid * 8]);
    gload16(B2t + bbase + kt, &B2s[buf][tid * 8]);
  };

  stage(0, 0);

  const int nkt = K >> 5;
  for (int t = 0; t < nkt; ++t) {
    const int cur = t & 1;
    if (t + 1 < nkt) {
      stage(cur ^ 1, (t + 1) << 5);
      asm volatile("s_waitcnt vmcnt(3)" ::: "memory");
    } else {
      asm volatile("s_waitcnt vmcnt(0)" ::: "memory");
    }
    __builtin_amdgcn_s_barrier();                        // B1

    bf16x8 af[2], b1f[4], b2f[4];
#pragma unroll
    for (int mi = 0; mi < 2; ++mi) {
      int r = wr * 32 + mi * 16 + r16;
      int cph = g ^ ((r >> 1) & 3);
      af[mi] = *(const bf16x8*)&As[cur][(r * 4 + cph) * 8];
    }
#pragma unroll
    for (int ni = 0; ni < 4; ++ni) {
      int r = wc * 64 + ni * 16 + r16;
      int cph = g ^ ((r >> 1) & 3);
      b1f[ni] = *(const bf16x8*)&B1s[cur][(r * 4 + cph) * 8];
      b2f[ni] = *(const bf16x8*)&B2s[cur][(r * 4 + cph) * 8];
    }
    __builtin_amdgcn_s_setprio(1);
#pragma unroll
    for (int mi = 0; mi < 2; ++mi)
#pragma unroll
      for (int ni = 0; ni < 4; ++ni) {
        acca[mi][ni] = mfma16(af[mi], b1f[ni], acca[mi][ni]);
        accg[mi][ni] = mfma16(af[mi], b2f[ni], accg[mi][ni]);
      }
    __builtin_amdgcn_s_setprio(0);

    __builtin_amdgcn_s_barrier();                        // B2
  }

#pragma unroll
  for (int ni = 0; ni < 4; ++ni) {
    int col = n0 + wc * 64 + ni * 16 + r16;
    float bva = ba[col], bvg = bg[col];
#pragma unroll
    for (int mi = 0; mi < 2; ++mi) {
#pragma unroll
      for (int rg = 0; rg < 4; ++rg) {
        int row = m0 + wr * 32 + mi * 16 + g * 4 + rg;
        float a  = acca[mi][ni][rg] + bva;
        float gt = accg[mi][ni][rg] + bvg;
        float gl = 0.5f * gt * (1.0f + erff(gt * 0.70710678f));
        out[(size_t)row * N + col] = f2bf(a * gl);
      }
    }
  }
}

// ---------------- flash attention v4 (counted vmcnt + raw barriers)
__global__ __launch_bounds__(256)
void attn_k(const u16* __restrict__ q, const u16* __restrict__ k,
            const u16* __restrict__ vt, u16* __restrict__ o,
            int kvlen, int seqk, int vstride)
{
  __shared__ __align__(16) u16 Ks[2][64 * 64];
  __shared__ __align__(16) u16 Vs[2][64 * 64];
  __shared__ __align__(16) u16 Ps[4][32 * 72];
  const int tid = threadIdx.x, lane = tid & 63, wave = tid >> 6;
  const int g = lane >> 4, r16 = lane & 15;
  const int bh = blockIdx.y;
  const int b = bh >> 4, h = bh & 15;
  const int q0 = blockIdx.x * 128 + wave * 32;
  const float C = 0.18033688f;   // log2(e)/8

  bf16x8 aq[2][2];
#pragma unroll
  for (int qs = 0; qs < 2; ++qs) {
    const size_t qoff = (size_t)(b * SEQ + q0 + qs * 16 + r16) * DIMN + h * DHEAD;
#pragma unroll
    for (int kc = 0; kc < 2; ++kc)
      aq[qs][kc] = *(const bf16x8*)&q[qoff + kc * 32 + g * 8];
  }
  // consume Q regs now so the compiler's waitcnt lands HERE, not inside the loop
  asm volatile("" :: "v"(aq[0][0]), "v"(aq[0][1]), "v"(aq[1][0]), "v"(aq[1][1]));

  f32x4 oacc[2][4] = {};
  float mi[2][4], li[2][4];
#pragma unroll
  for (int qs = 0; qs < 2; ++qs)
#pragma unroll
    for (int rg = 0; rg < 4; ++rg) { mi[qs][rg] = -3e38f; li[qs][rg] = 0.f; }

  const size_t vtbase = (size_t)(b * HEADS + h) * DHEAD * vstride;
  const size_t kbase  = (size_t)b * seqk * DIMN + h * DHEAD;
  const int nkv = (kvlen + 63) >> 6;

  auto stage = [&](int buf, int kv0) {
#pragma unroll
    for (int i = 0; i < 2; ++i) {
      const int c = tid + i * 256;
      const int row = c >> 3, ch = c & 7;
      const int chs = ch ^ (row & 7);
      int kr = kv0 + row; if (kr > kvlen - 1) kr = kvlen - 1;
      gload16(k + kbase + (size_t)kr * DIMN + chs * 8, &Ks[buf][c * 8]);
    }
#pragma unroll
    for (int i = 0; i < 2; ++i) {
      const int c = tid + i * 256;
      const int row = c >> 3, ch = c & 7;
      const int chs = ch ^ (row & 7);
      gload16(vt + vtbase + (size_t)row * vstride + kv0 + chs * 8, &Vs[buf][c * 8]);
    }
  };

  stage(0, 0);

  for (int kvb = 0; kvb < nkv; ++kvb) {
    const int kv0 = kvb * 64;
    const int cur = kvb & 1;
    if (kvb + 1 < nkv) {
      stage(cur ^ 1, kv0 + 64);
      asm volatile("s_waitcnt vmcnt(4)" ::: "memory");
    } else {
      asm volatile("s_waitcnt vmcnt(0)" ::: "memory");
    }
    __builtin_amdgcn_s_barrier();                        // B1

    // ---- QK^T: 16 MFMA
    f32x4 sa[2][4];
#pragma unroll
    for (int qs = 0; qs < 2; ++qs)
#pragma unroll
      for (int st = 0; st < 4; ++st) sa[qs][st] = (f32x4){0.f, 0.f, 0.f, 0.f};
    __builtin_amdgcn_s_setprio(1);
#pragma unroll
    for (int st = 0; st < 4; ++st) {
      const int kvr = st * 16 + r16;
#pragma unroll
      for (int kc = 0; kc < 2; ++kc) {
        const int chs = (kc * 4 + g) ^ (kvr & 7);
        const bf16x8 kf = *(const bf16x8*)&Ks[cur][kvr * 64 + chs * 8];
        sa[0][st] = mfma16(aq[0][kc], kf, sa[0][st]);
        sa[1][st] = mfma16(aq[1][kc], kf, sa[1][st]);
      }
    }
    __builtin_amdgcn_s_setprio(0);

    // ---- tail mask (cross-attn last tile only)
    if (kv0 + 64 > kvlen) {
#pragma unroll
      for (int st = 0; st < 4; ++st)
        if (kv0 + st * 16 + r16 >= kvlen) {
#pragma unroll
          for (int qs = 0; qs < 2; ++qs)
#pragma unroll
            for (int rg = 0; rg < 4; ++rg) sa[qs][st][rg] = -3e38f;
        }
    }

    // ---- defer-max check
    float bad = 0.f;
    float m4v[2][4];
#pragma unroll
    for (int qs = 0; qs < 2; ++qs)
#pragma unroll
      for (int rg = 0; rg < 4; ++rg) {
        float m4 = fmaxf(fmaxf(sa[qs][0][rg], sa[qs][1][rg]),
                         fmaxf(sa[qs][2][rg], sa[qs][3][rg]));
        m4v[qs][rg] = m4;
        bad = fmaxf(bad, m4 - mi[qs][rg]);
      }
    if (__any(bad > 16.0f)) {
#pragma unroll
      for (int qs = 0; qs < 2; ++qs)
#pragma unroll
        for (int rg = 0; rg < 4; ++rg) {
          float mx = m4v[qs][rg];
#pragma unroll
          for (int off = 1; off < 16; off <<= 1) mx = fmaxf(mx, __shfl_xor(mx, off));
          const float nm = fmaxf(mi[qs][rg], mx);
          const float corr = __builtin_amdgcn_exp2f((mi[qs][rg] - nm) * C);
          mi[qs][rg] = nm;
          li[qs][rg] *= corr;
#pragma unroll
          for (int ds = 0; ds < 4; ++ds) oacc[qs][ds][rg] *= corr;
        }
    }

    // ---- P = exp, lane-local li accumulate, packed bf16 store
#pragma unroll
    for (int qs = 0; qs < 2; ++qs) {
#pragma unroll
      for (int rg = 0; rg < 4; ++rg) {
        const float mc = mi[qs][rg] * C;
        const float p0 = __builtin_amdgcn_exp2f(__builtin_fmaf(sa[qs][0][rg], C, -mc));
        const float p1 = __builtin_amdgcn_exp2f(__builtin_fmaf(sa[qs][1][rg], C, -mc));
        const float p2 = __builtin_amdgcn_exp2f(__builtin_fmaf(sa[qs][2][rg], C, -mc));
        const float p3 = __builtin_amdgcn_exp2f(__builtin_fmaf(sa[qs][3][rg], C, -mc));
        li[qs][rg] += (p0 + p1) + (p2 + p3);
        unsigned lo, hi;
        asm("v_cvt_pk_bf16_f32 %0, %1, %2" : "=v"(lo) : "v"(p0), "v"(p1));
        asm("v_cvt_pk_bf16_f32 %0, %1, %2" : "=v"(hi) : "v"(p2), "v"(p3));
        const int prow = qs * 16 + g * 4 + rg;
        uint2 pk; pk.x = lo; pk.y = hi;
        *(uint2*)&Ps[wave][prow * 72 + r16 * 4] = pk;
      }
    }

    // ---- PV: 16 MFMA
    __builtin_amdgcn_s_setprio(1);
#pragma unroll
    for (int kc = 0; kc < 2; ++kc) {
      const bf16x8 pa0 = *(const bf16x8*)&Ps[wave][(r16)      * 72 + kc * 32 + g * 8];
      const bf16x8 pa1 = *(const bf16x8*)&Ps[wave][(16 + r16) * 72 + kc * 32 + g * 8];
#pragma unroll
      for (int ds = 0; ds < 4; ++ds) {
        const int dr = ds * 16 + r16;
        const int chs = (kc * 4 + g) ^ (dr & 7);
        const bf16x8 vf = *(const bf16x8*)&Vs[cur][dr * 64 + chs * 8];
        oacc[0][ds] = mfma16(pa0, vf, oacc[0][ds]);
        oacc[1][ds] = mfma16(pa1, vf, oacc[1][ds]);
      }
    }
    __builtin_amdgcn_s_setprio(0);

    __builtin_amdgcn_s_barrier();                        // B2
  }

#pragma unroll
  for (int qs = 0; qs < 2; ++qs)
#pragma unroll
    for (int rg = 0; rg < 4; ++rg) {
      float s = li[qs][rg];
#pragma unroll
      for (int off = 1; off < 16; off <<= 1) s += __shfl_xor(s, off);
      li[qs][rg] = s;
    }

#pragma unroll
  for (int qs = 0; qs < 2; ++qs)
#pragma unroll
    for (int rg = 0; rg < 4; ++rg) {
      const float inv = 1.0f / li[qs][rg];
      const int row = q0 + qs * 16 + g * 4 + rg;
      const size_t base = (size_t)(b * SEQ + row) * DIMN + h * DHEAD;
#pragma unroll
      for (int ds = 0; ds < 4; ++ds)
        o[base + ds * 16 + r16] = f2bf(oacc[qs][ds][rg] * inv);
    }
}

extern "C" void kernel_launch(void* const* d_in, const int* in_sizes, int n_in,
                              void* d_out, int out_size, void* d_ws, size_t ws_size,
                              hipStream_t stream)
{
  const float* x   = (const float*)d_in[0];
  const float* ctx = (const float*)d_in[1];
  const float* Wq1 = (const float*)d_in[2];
  const float* Wk1 = (const float*)d_in[3];
  const float* Wv1 = (const float*)d_in[4];
  const float* Wo1 = (const float*)d_in[5];
  const float* bo1 = (const float*)d_in[6];
  const float* Wq2 = (const float*)d_in[7];
  const float* Wk2 = (const float*)d_in[8];
  const float* Wv2 = (const float*)d_in[9];
  const float* Wo2 = (const float*)d_in[10];
  const float* bo2 = (const float*)d_in[11];
  const float* Wp  = (const float*)d_in[12];
  const float* bp  = (const float*)d_in[13];
  const float* W2  = (const float*)d_in[14];
  const float* b2  = (const float*)d_in[15];
  const float* g1  = (const float*)d_in[16];
  const float* be1 = (const float*)d_in[17];
  const float* g2  = (const float*)d_in[18];
  const float* be2 = (const float*)d_in[19];
  const float* g3  = (const float*)d_in[20];
  const float* be3 = (const float*)d_in[21];

  char* ws = (char*)d_ws;
  size_t off = 0;
  auto alloc = [&](size_t bytes) -> void* {
    void* p = ws + off;
    off += (bytes + 255) & ~(size_t)255;
    return p;
  };

  u16* WqT1 = (u16*)alloc((size_t)1024 * 1024 * 2);   // contiguous with WkT1, WvT1
  u16* WkT1 = (u16*)alloc((size_t)1024 * 1024 * 2);
  u16* WvT1 = (u16*)alloc((size_t)1024 * 1024 * 2);
  u16* WoT1 = (u16*)alloc((size_t)1024 * 1024 * 2);
  u16* WqT2 = (u16*)alloc((size_t)1024 * 1024 * 2);
  u16* WkT2 = (u16*)alloc((size_t)1024 * 768 * 2);    // contiguous with WvT2
  u16* WvT2 = (u16*)alloc((size_t)1024 * 768 * 2);
  u16* WoT2 = (u16*)alloc((size_t)1024 * 1024 * 2);
  u16* WpT  = (u16*)alloc((size_t)8192 * 1024 * 2);
  u16* W2T  = (u16*)alloc((size_t)1024 * 4096 * 2);
  float* x1f = (float*)alloc((size_t)NTOK * DIMN * 4);
  float* x2f = (float*)alloc((size_t)NTOK * DIMN * 4);
  u16* ctxb = (u16*)alloc((size_t)CTOK * CTXD * 2);
  u16* k2b  = (u16*)alloc((size_t)CTOK * DIMN * 2);
  u16* vt2b = (u16*)alloc((size_t)2 * HEADS * DHEAD * 128 * 2);
  u16* hb   = (u16*)alloc((size_t)NTOK * DIMN * 2);
  u16* qb   = (u16*)alloc((size_t)NTOK * DIMN * 2);
  u16* kb   = (u16*)alloc((size_t)NTOK * DIMN * 2);
  u16* vtb  = (u16*)alloc((size_t)NTOK * DIMN * 2);
  u16* ab   = (u16*)alloc((size_t)NTOK * DIMN * 2);
  u16* ub   = qb; // reuse qb..ab region (32MB) for FF intermediate [4096][4096]

  dim3 blk(256);
  dim3 blk5(512);

  wconv_k<<<dim3(16, 16), blk, 0, stream>>>(Wq1, WqT1, 1024, 1024);
  wconv_k<<<dim3(16, 16), blk, 0, stream>>>(Wk1, WkT1, 1024, 1024);
  wconv_k<<<dim3(16, 16), blk, 0, stream>>>(Wv1, WvT1, 1024, 1024);
  wconv_k<<<dim3(16, 16), blk, 0, stream>>>(Wo1, WoT1, 1024, 1024);
  wconv_k<<<dim3(16, 16), blk, 0, stream>>>(Wq2, WqT2, 1024, 1024);
  wconv_k<<<dim3(16, 12), blk, 0, stream>>>(Wk2, WkT2, 768, 1024);
  wconv_k<<<dim3(16, 12), blk, 0, stream>>>(Wv2, WvT2, 768, 1024);
  wconv_k<<<dim3(16, 16), blk, 0, stream>>>(Wo2, WoT2, 1024, 1024);
  wconv_k<<<dim3(128, 16), blk, 0, stream>>>(Wp, WpT, 1024, 8192);
  wconv_k<<<dim3(16, 64), blk, 0, stream>>>(W2, W2T, 4096, 1024);
  cconv_k<<<dim3((CTOK * CTXD + 255) / 256), blk, 0, stream>>>(ctx, ctxb, CTOK * CTXD);

  // ---- self attention block (QKV fused: WqT1/WkT1/WvT1 contiguous, N=3072)
  ln_k<<<NTOK, 256, 0, stream>>>(x, g1, be1, hb);
  gemm_k<4><<<dim3(32, 24), blk5, 0, stream>>>(hb, WqT1, NTOK, 3072, 1024, nullptr, nullptr, qb, nullptr, SEQ, SEQ, kb, vtb);
  attn_k<<<dim3(16, 32), blk, 0, stream>>>(qb, kb, vtb, ab, SEQ, SEQ, SEQ);
  gemm_k<2><<<dim3(32, 8), blk5, 0, stream>>>(ab, WoT1, NTOK, 1024, 1024, bo1, x, nullptr, x1f, 0, 0, nullptr, nullptr);

  // ---- cross attention block (K2+V2 fused over ctx, N=2048)
  ln_k<<<NTOK, 256, 0, stream>>>(x1f, g2, be2, hb);
  gemm_k<0><<<dim3(32, 8), blk5, 0, stream>>>(hb, WqT2, NTOK, 1024, 1024, nullptr, nullptr, qb, nullptr, 0, 0, nullptr, nullptr);
  gemm_k<5><<<dim3(2, 16), blk5, 0, stream>>>(ctxb, WkT2, CTOK, 2048, 768, nullptr, nullptr, k2b, nullptr, NCTX, 128, nullptr, vt2b);
  attn_k<<<dim3(16, 32), blk, 0, stream>>>(qb, k2b, vt2b, ab, NCTX, NCTX, 128);
  gemm_k<2><<<dim3(32, 8), blk5, 0, stream>>>(ab, WoT2, NTOK, 1024, 1024, bo2, x1f, nullptr, x2f, 0, 0, nullptr, nullptr);

  // ---- GEGLU FF block
  ln_k<<<NTOK, 256, 0, stream>>>(x2f, g3, be3, hb);
  geglu_k<<<dim3(32, 32), blk5, 0, stream>>>(hb, WpT, WpT + (size_t)4096 * 1024, bp, bp + 4096, ub, NTOK, FFH);
  gemm_k<2><<<dim3(32, 8), blk5, 0, stream>>>(ub, W2T, NTOK, 1024, 4096, b2, x2f, nullptr, (float*)d_out, 0, 0, nullptr, nullptr);

  (void)in_sizes; (void)n_in; (void)out_size; (void)ws_size;
}